// Round 7
// baseline (419.340 us; speedup 1.0000x reference)
//
#include <hip/hip_runtime.h>
#include <hip/hip_bf16.h>

#define D 128
#define EPS 1e-5f

typedef __attribute__((ext_vector_type(8))) short short8;
typedef __attribute__((ext_vector_type(4))) float float4v;

__device__ inline ushort f2bf(float f) {
    __hip_bfloat16 b = __float2bfloat16(f);
    return *reinterpret_cast<ushort*>(&b);
}
__device__ inline float bf_lo(uint u) { return __uint_as_float(u << 16); }
__device__ inline float bf_hi(uint u) { return __uint_as_float(u & 0xffff0000u); }

// ---------- K1: LN1 + ReLU, fp32 in -> bf16 out. One wave per node. ----------
__global__ void k_ln1(const float* __restrict__ x, const int* __restrict__ ntp,
                      const float* __restrict__ gamma, const float* __restrict__ beta,
                      ushort* __restrict__ y, int N) {
    int n = blockIdx.x * 4 + (threadIdx.x >> 6);
    if (n >= N) return;
    int l = threadIdx.x & 63;
    float2 v = *(const float2*)(x + (size_t)n * D + 2 * l);
    float s = v.x + v.y, s2 = v.x * v.x + v.y * v.y;
    #pragma unroll
    for (int o = 32; o; o >>= 1) { s += __shfl_xor(s, o, 64); s2 += __shfl_xor(s2, o, 64); }
    float mu = s * (1.0f / D);
    float var = s2 * (1.0f / D) - mu * mu;
    float inv = rsqrtf(var + EPS);
    int t = ntp[n];
    float2 g = *(const float2*)(gamma + t * D + 2 * l);
    float2 b = *(const float2*)(beta + t * D + 2 * l);
    float a0 = fmaxf((v.x - mu) * inv * g.x + b.x, 0.0f);
    float a1 = fmaxf((v.y - mu) * inv * g.y + b.y, 0.0f);
    ((uint*)(y + (size_t)n * D))[l] = ((uint)f2bf(a1) << 16) | f2bf(a0);
}

// ---------- K2: weights -> bf16 in MFMA B-FRAGMENT order ----------------------
// m==0: W_root, 1..8: W_rel[m-1], 9..12: W_mlp[m-9].
__global__ void k_cvt(const float* __restrict__ Wrel, const float* __restrict__ Wroot,
                      const float* __restrict__ Wmlp, ushort* __restrict__ Wt) {
    __shared__ ushort t[128][136];
    int m = blockIdx.x;
    const float* src = (m == 0) ? Wroot
                     : (m <= 8) ? Wrel + (size_t)(m - 1) * D * D
                                : Wmlp + (size_t)(m - 9) * D * D;
    for (int i = threadIdx.x; i < D * D; i += 256) {
        int k = i >> 7, n = i & 127;
        t[n][k] = f2bf(src[i]);
    }
    __syncthreads();
    ushort* dst = Wt + (size_t)m * D * D;
    for (int i = threadIdx.x; i < D * D; i += 256) {
        int frag = i >> 9;            // 0..31  (nt*4+ks)
        int lane = (i >> 3) & 63;
        int j = i & 7;
        int nt = frag >> 2, ks = frag & 3;
        int n = nt * 16 + (lane & 15);
        int k = ks * 32 + (lane >> 4) * 8 + j;
        dst[i] = t[n][k];
    }
}

// ---------- edge bucketing by dst: hist, 2-level scan, scatter ----------------
__global__ void k_ehist(const int* __restrict__ edst, int* __restrict__ hist, int E) {
    int e = blockIdx.x * blockDim.x + threadIdx.x;
    if (e < E) atomicAdd(&hist[edst[e]], 1);
}
__global__ void k_scan1(const int* __restrict__ hist, int* __restrict__ blocksum, int N) {
    __shared__ int ps[256];
    int t = threadIdx.x;
    int base = blockIdx.x * 1024 + t * 4;
    int s = 0;
    #pragma unroll
    for (int k = 0; k < 4; ++k) { int i = base + k; if (i < N) s += hist[i]; }
    ps[t] = s;
    __syncthreads();
    if (t == 0) {
        int tot = 0;
        for (int i = 0; i < 256; ++i) tot += ps[i];
        blocksum[blockIdx.x] = tot;
    }
}
__global__ void k_scan2(int* __restrict__ blocksum, int* __restrict__ offs, int B, int N) {
    if (threadIdx.x == 0) {
        int o = 0;
        for (int b = 0; b < B; ++b) { int c = blocksum[b]; blocksum[b] = o; o += c; }
        offs[N] = o;
    }
}
__global__ void k_scan3(const int* __restrict__ hist, const int* __restrict__ blockoff,
                        int* __restrict__ offs, int* __restrict__ cursor, int N) {
    __shared__ int ps[256];
    int t = threadIdx.x;
    int base = blockIdx.x * 1024 + t * 4;
    int s = 0;
    #pragma unroll
    for (int k = 0; k < 4; ++k) { int i = base + k; if (i < N) s += hist[i]; }
    int mysum = s;
    ps[t] = s;
    __syncthreads();
    for (int off = 1; off < 256; off <<= 1) {
        int v = (t >= off) ? ps[t - off] : 0;
        __syncthreads();
        ps[t] += v;
        __syncthreads();
    }
    int run = ps[t] - mysum + blockoff[blockIdx.x];
    #pragma unroll
    for (int k = 0; k < 4; ++k) {
        int i = base + k;
        if (i < N) { offs[i] = run; cursor[i] = run; run += hist[i]; }
    }
}
__global__ void k_escatter(const int* __restrict__ edst, const int* __restrict__ esrc,
                           const int* __restrict__ etyp, int* __restrict__ cursor,
                           uint* __restrict__ epack, int E) {
    int e = blockIdx.x * blockDim.x + threadIdx.x;
    if (e < E) {
        int p = atomicAdd(&cursor[edst[e]], 1);
        epack[p] = ((uint)etyp[e] << 28) | (uint)esrc[e];
    }
}

// ---------- K3: z[v][r] = sum of y[src] over edges (dst=v, type=r) ------------
// one wave per dst; 8 register float2 accumulators; 64-wide epack broadcast;
// 4-way unrolled inner loop for load-level parallelism.
__global__ void k_zagg(const ushort* __restrict__ ybuf, const int* __restrict__ offs,
                       const uint* __restrict__ epack, ushort* __restrict__ zbuf, int N) {
    int wave = threadIdx.x >> 6;
    int l = threadIdx.x & 63;
    int v = blockIdx.x * 4 + wave;
    if (v >= N) return;
    float2 ac[8];
    #pragma unroll
    for (int r = 0; r < 8; ++r) ac[r] = make_float2(0.f, 0.f);
    const uint* yb = (const uint*)ybuf;
    int j = offs[v], e1 = offs[v + 1];
    while (j < e1) {
        int chunk = min(64, e1 - j);
        uint pl = (j + l < e1) ? epack[j + l] : 0;
        int i = 0;
        for (; i + 3 < chunk; i += 4) {
            uint p0 = __shfl(pl, i, 64);
            uint p1 = __shfl(pl, i + 1, 64);
            uint p2 = __shfl(pl, i + 2, 64);
            uint p3 = __shfl(pl, i + 3, 64);
            uint u0 = yb[(size_t)(p0 & 0x0FFFFFFFu) * 64 + l];
            uint u1 = yb[(size_t)(p1 & 0x0FFFFFFFu) * 64 + l];
            uint u2 = yb[(size_t)(p2 & 0x0FFFFFFFu) * 64 + l];
            uint u3 = yb[(size_t)(p3 & 0x0FFFFFFFu) * 64 + l];
            { float2* a = &ac[p0 >> 28]; a->x += bf_lo(u0); a->y += bf_hi(u0); }
            { float2* a = &ac[p1 >> 28]; a->x += bf_lo(u1); a->y += bf_hi(u1); }
            { float2* a = &ac[p2 >> 28]; a->x += bf_lo(u2); a->y += bf_hi(u2); }
            { float2* a = &ac[p3 >> 28]; a->x += bf_lo(u3); a->y += bf_hi(u3); }
        }
        for (; i < chunk; ++i) {
            uint p = __shfl(pl, i, 64);
            uint u = yb[(size_t)(p & 0x0FFFFFFFu) * 64 + l];
            float2* a = &ac[p >> 28];
            a->x += bf_lo(u); a->y += bf_hi(u);
        }
        j += chunk;
    }
    uint* zrow = (uint*)(zbuf + (size_t)v * 1024);
    #pragma unroll
    for (int r = 0; r < 8; ++r)
        zrow[r * 64 + l] = ((uint)f2bf(ac[r].y) << 16) | f2bf(ac[r].x);
}

// ---------- K4: agg = [y|z] @ [Wroot;Wrel] (K=1152) + x, fused LN2+ReLU -------
// grid ceil(N/64), block 256 (4 waves x 16 rows). W staged in LDS (frag order).
// Writes x2p/y2p at PERMUTED slot pos[row] so k_mlp reads sequentially.
__launch_bounds__(256)
__global__ void k_gemm2(const ushort* __restrict__ ybuf, const ushort* __restrict__ zbuf,
                        const ushort* __restrict__ Wt, const float* __restrict__ x,
                        const int* __restrict__ ntp, const int* __restrict__ pos,
                        const float* __restrict__ gamma, const float* __restrict__ beta,
                        float* __restrict__ x2p, ushort* __restrict__ y2p, int N) {
    __shared__ ushort wsm[16384];                       // 32 KB
    int tid = threadIdx.x;
    int wave = tid >> 6, lane = tid & 63;
    int quad = lane >> 4, l15 = lane & 15;
    int base = blockIdx.x * 64 + wave * 16;
    int arow = min(base + l15, N - 1);
    const ushort* yrow = ybuf + (size_t)arow * 128;
    const ushort* zrow = zbuf + (size_t)arow * 1024;

    float4v acc[8];
    #pragma unroll
    for (int nt = 0; nt < 8; ++nt) acc[nt] = (float4v){0.f, 0.f, 0.f, 0.f};

    for (int mat = 0; mat < 9; ++mat) {
        __syncthreads();                                // protect wsm overwrite
        const ushort* wsrc = Wt + (size_t)mat * 16384;
        #pragma unroll
        for (int jj = 0; jj < 8; ++jj)
            *(uint4*)(wsm + jj * 2048 + tid * 8) = *(const uint4*)(wsrc + jj * 2048 + tid * 8);
        __syncthreads();
        const ushort* ap = (mat == 0) ? yrow : zrow + (mat - 1) * 128;
        short8 a[4];
        #pragma unroll
        for (int ks = 0; ks < 4; ++ks) a[ks] = *(const short8*)(ap + ks * 32 + quad * 8);
        #pragma unroll
        for (int nt = 0; nt < 8; ++nt) {
            #pragma unroll
            for (int ks = 0; ks < 4; ++ks) {
                short8 b = *(const short8*)(wsm + (((nt * 4 + ks) * 64 + lane) << 3));
                acc[nt] = __builtin_amdgcn_mfma_f32_16x16x32_bf16(a[ks], b, acc[nt], 0, 0, 0);
            }
        }
    }

    // epilogue: x2 = x + acc; LN2 + ReLU -> y2 (stored at permuted slots)
    float s[4] = {0.f, 0.f, 0.f, 0.f}, s2[4] = {0.f, 0.f, 0.f, 0.f};
    #pragma unroll
    for (int nt = 0; nt < 8; ++nt) {
        int col = nt * 16 + l15;
        #pragma unroll
        for (int r = 0; r < 4; ++r) {
            int row = base + quad * 4 + r;
            float xv = (row < N) ? x[(size_t)row * D + col] : 0.f;
            float t = acc[nt][r] + xv;
            acc[nt][r] = t;
            s[r] += t; s2[r] += t * t;
        }
    }
    #pragma unroll
    for (int r = 0; r < 4; ++r) {
        #pragma unroll
        for (int o = 1; o < 16; o <<= 1) {
            s[r]  += __shfl_xor(s[r],  o, 64);
            s2[r] += __shfl_xor(s2[r], o, 64);
        }
    }
    #pragma unroll
    for (int r = 0; r < 4; ++r) {
        int row = base + quad * 4 + r;
        int rc = min(row, N - 1);
        int t = ntp[rc];
        int pp = pos[rc];
        float mu  = s[r] * (1.0f / D);
        float var = s2[r] * (1.0f / D) - mu * mu;
        float inv = rsqrtf(var + EPS);
        #pragma unroll
        for (int nt = 0; nt < 8; ++nt) {
            int col = nt * 16 + l15;
            float xx = acc[nt][r];
            float yn = fmaxf((xx - mu) * inv * gamma[t * D + col] + beta[t * D + col], 0.f);
            if (row < N) {
                x2p[(size_t)pp * D + col] = xx;
                y2p[(size_t)pp * D + col] = f2bf(yn);
            }
        }
    }
}

// ---------- node-type bucketing (64-aligned) ----------------------------------
__global__ void k_nhist(const int* __restrict__ ntp, int* __restrict__ small, int N) {
    __shared__ int c[4];
    if (threadIdx.x < 4) c[threadIdx.x] = 0;
    __syncthreads();
    int n = blockIdx.x * blockDim.x + threadIdx.x;
    if (n < N) atomicAdd(&c[ntp[n]], 1);
    __syncthreads();
    if (threadIdx.x < 4 && c[threadIdx.x]) atomicAdd(&small[threadIdx.x], c[threadIdx.x]);
}
__global__ void k_prep(int* __restrict__ small, int gridMlp) {
    __shared__ int st[5];
    if (threadIdx.x == 0) {
        int o = 0;
        for (int t = 0; t < 4; ++t) {
            small[8 + t] = o;
            st[t] = o;
            o += (small[t] + 63) & ~63;
        }
        small[12] = o;
        st[4] = o;
    }
    __syncthreads();
    int* tob = small + 16;
    for (int b = threadIdx.x; b < gridMlp; b += blockDim.x) {
        int b64 = b * 64;
        int t = -1;
        for (int i = 0; i < 4; ++i)
            if (b64 >= st[i] && b64 < st[i + 1]) t = i;
        tob[b] = t;
    }
}
// block-aggregated ranks; also emits pos[n] (inverse permutation)
__global__ void k_nscatter(const int* __restrict__ ntp, int* __restrict__ small,
                           int* __restrict__ perm_pad, int* __restrict__ pos, int N) {
    __shared__ int cnt[4], base[4];
    int tid = threadIdx.x;
    if (tid < 4) cnt[tid] = 0;
    __syncthreads();
    int n = blockIdx.x * blockDim.x + tid;
    int t = 0, rank = 0;
    bool valid = (n < N);
    if (valid) { t = ntp[n]; rank = atomicAdd(&cnt[t], 1); }
    __syncthreads();
    if (tid < 4) base[tid] = cnt[tid] ? atomicAdd(&small[4 + tid], cnt[tid]) : 0;
    __syncthreads();
    if (valid) {
        int p = small[8 + t] + base[t] + rank;
        perm_pad[p] = n;
        pos[n] = p;
    }
}

// ---------- K5: MLP MFMA + residual + bias; A/x2 sequential, out scattered ----
__global__ void k_mlp(const ushort* __restrict__ y2p, const float* __restrict__ x2p,
                      const int* __restrict__ perm_pad, const int* __restrict__ small,
                      const ushort* __restrict__ Wt, const float* __restrict__ bmlp,
                      float* __restrict__ out, int N) {
    int t = small[16 + blockIdx.x];
    if (t < 0) return;
    int wave = threadIdx.x >> 6;
    int lane = threadIdx.x & 63;
    int quad = lane >> 4;
    int base = blockIdx.x * 64 + wave * 16;
    short8 a[4];
    const ushort* yrow = y2p + (size_t)(base + (lane & 15)) * D + quad * 8;
    #pragma unroll
    for (int ks = 0; ks < 4; ++ks) a[ks] = *(const short8*)(yrow + ks * 32);
    int srow[4];
    #pragma unroll
    for (int r = 0; r < 4; ++r) srow[r] = perm_pad[base + quad * 4 + r];
    const ushort* Wb = Wt + (size_t)(9 + t) * D * D;
    #pragma unroll
    for (int nt = 0; nt < 8; ++nt) {
        float4v acc = {0.f, 0.f, 0.f, 0.f};
        #pragma unroll
        for (int ks = 0; ks < 4; ++ks) {
            short8 b = *(const short8*)(Wb + (((nt * 4 + ks) * 64 + lane) << 3));
            acc = __builtin_amdgcn_mfma_f32_16x16x32_bf16(a[ks], b, acc, 0, 0, 0);
        }
        int col = nt * 16 + (lane & 15);
        float bm = bmlp[t * D + col];
        #pragma unroll
        for (int r = 0; r < 4; ++r) {
            if (srow[r] >= 0)
                out[(size_t)srow[r] * D + col] =
                    x2p[(size_t)(base + quad * 4 + r) * D + col] + acc[r] + bm;
        }
    }
}

// ---------- launch ------------------------------------------------------------
extern "C" void kernel_launch(void* const* d_in, const int* in_sizes, int n_in,
                              void* d_out, int out_size, void* d_ws, size_t ws_size,
                              hipStream_t stream) {
    const float* x          = (const float*)d_in[0];
    const int*   esrc       = (const int*)d_in[1];
    const int*   edst       = (const int*)d_in[2];
    const int*   ntyp       = (const int*)d_in[3];
    const int*   etyp       = (const int*)d_in[4];
    const float* conv_gamma = (const float*)d_in[5];
    const float* conv_beta  = (const float*)d_in[6];
    const float* W_rel      = (const float*)d_in[7];
    const float* W_root     = (const float*)d_in[8];
    const float* mlp_gamma  = (const float*)d_in[9];
    const float* mlp_beta   = (const float*)d_in[10];
    const float* W_mlp      = (const float*)d_in[11];
    const float* b_mlp      = (const float*)d_in[12];
    float* out = (float*)d_out;

    int N = in_sizes[0] / D;
    int E = in_sizes[1];
    int gridMlp = (N + 252 + 63) / 64;
    int scanB = (N + 1023) / 1024;

    char* p = (char*)d_ws;
    auto take = [&p](size_t bytes) { char* q = p; p += (bytes + 255) & ~(size_t)255; return q; };
    ushort* ybuf   = (ushort*)take((size_t)N * D * 2);
    ushort* y2p    = (ushort*)take((size_t)(N + 256) * D * 2);
    ushort* zbuf   = (ushort*)take((size_t)N * 1024 * 2);
    float*  x2p    = (float*)take((size_t)(N + 256) * D * 4);
    ushort* Wt     = (ushort*)take((size_t)13 * D * D * 2);
    int*    hist   = (int*)take((size_t)N * 4);
    int*    offs   = (int*)take((size_t)(N + 1) * 4);
    int*    cursor = (int*)take((size_t)N * 4);
    uint*   epack  = (uint*)take((size_t)E * 4);
    int*    permpad= (int*)take((size_t)(N + 256) * 4);
    int*    pos    = (int*)take((size_t)N * 4);
    int*    small  = (int*)take((size_t)(16 + gridMlp) * 4);
    int*    bsum   = (int*)take((size_t)scanB * 4);

    hipMemsetAsync(hist, 0, (size_t)N * 4, stream);
    hipMemsetAsync(small, 0, 16 * 4, stream);
    hipMemsetAsync(permpad, 0xFF, (size_t)(N + 256) * 4, stream);

    k_ln1<<<(N + 3) / 4, 256, 0, stream>>>(x, ntyp, conv_gamma, conv_beta, ybuf, N);
    k_cvt<<<13, 256, 0, stream>>>(W_rel, W_root, W_mlp, Wt);

    k_ehist<<<(E + 255) / 256, 256, 0, stream>>>(edst, hist, E);
    k_scan1<<<scanB, 256, 0, stream>>>(hist, bsum, N);
    k_scan2<<<1, 64, 0, stream>>>(bsum, offs, scanB, N);
    k_scan3<<<scanB, 256, 0, stream>>>(hist, bsum, offs, cursor, N);
    k_escatter<<<(E + 255) / 256, 256, 0, stream>>>(edst, esrc, etyp, cursor, epack, E);

    k_nhist<<<(N + 255) / 256, 256, 0, stream>>>(ntyp, small, N);
    k_prep<<<1, 256, 0, stream>>>(small, gridMlp);
    k_nscatter<<<(N + 255) / 256, 256, 0, stream>>>(ntyp, small, permpad, pos, N);

    k_zagg<<<(N + 3) / 4, 256, 0, stream>>>(ybuf, offs, epack, zbuf, N);

    k_gemm2<<<(N + 63) / 64, 256, 0, stream>>>(ybuf, zbuf, Wt, x, ntyp, pos,
                                               mlp_gamma, mlp_beta, x2p, y2p, N);

    k_mlp<<<gridMlp, 256, 0, stream>>>(y2p, x2p, permpad, small, Wt, b_mlp, out, N);
}

// Round 8
// 337.647 us; speedup vs baseline: 1.2419x; 1.2419x over previous
//
#include <hip/hip_runtime.h>
#include <hip/hip_bf16.h>

#define D 128
#define EPS 1e-5f

typedef __attribute__((ext_vector_type(8))) short short8;
typedef __attribute__((ext_vector_type(4))) float float4v;

__device__ inline ushort f2bf(float f) {
    __hip_bfloat16 b = __float2bfloat16(f);
    return *reinterpret_cast<ushort*>(&b);
}
__device__ inline float bf_lo(uint u) { return __uint_as_float(u << 16); }
__device__ inline float bf_hi(uint u) { return __uint_as_float(u & 0xffff0000u); }

// ---------- K1: LN1 + ReLU, fp32 in -> bf16 out. One wave per node. ----------
__global__ void k_ln1(const float* __restrict__ x, const int* __restrict__ ntp,
                      const float* __restrict__ gamma, const float* __restrict__ beta,
                      ushort* __restrict__ y, int N) {
    int n = blockIdx.x * 4 + (threadIdx.x >> 6);
    if (n >= N) return;
    int l = threadIdx.x & 63;
    float2 v = *(const float2*)(x + (size_t)n * D + 2 * l);
    float s = v.x + v.y, s2 = v.x * v.x + v.y * v.y;
    #pragma unroll
    for (int o = 32; o; o >>= 1) { s += __shfl_xor(s, o, 64); s2 += __shfl_xor(s2, o, 64); }
    float mu = s * (1.0f / D);
    float var = s2 * (1.0f / D) - mu * mu;
    float inv = rsqrtf(var + EPS);
    int t = ntp[n];
    float2 g = *(const float2*)(gamma + t * D + 2 * l);
    float2 b = *(const float2*)(beta + t * D + 2 * l);
    float a0 = fmaxf((v.x - mu) * inv * g.x + b.x, 0.0f);
    float a1 = fmaxf((v.y - mu) * inv * g.y + b.y, 0.0f);
    ((uint*)(y + (size_t)n * D))[l] = ((uint)f2bf(a1) << 16) | f2bf(a0);
}

// ---------- K2: weights -> bf16 in MFMA B-FRAGMENT order ----------------------
// m==0: W_root, 1..8: W_rel[m-1], 9..12: W_mlp[m-9].
__global__ void k_cvt(const float* __restrict__ Wrel, const float* __restrict__ Wroot,
                      const float* __restrict__ Wmlp, ushort* __restrict__ Wt) {
    __shared__ ushort t[128][136];
    int m = blockIdx.x;
    const float* src = (m == 0) ? Wroot
                     : (m <= 8) ? Wrel + (size_t)(m - 1) * D * D
                                : Wmlp + (size_t)(m - 9) * D * D;
    for (int i = threadIdx.x; i < D * D; i += 256) {
        int k = i >> 7, n = i & 127;
        t[n][k] = f2bf(src[i]);
    }
    __syncthreads();
    ushort* dst = Wt + (size_t)m * D * D;
    for (int i = threadIdx.x; i < D * D; i += 256) {
        int frag = i >> 9;            // 0..31  (nt*4+ks)
        int lane = (i >> 3) & 63;
        int j = i & 7;
        int nt = frag >> 2, ks = frag & 3;
        int n = nt * 16 + (lane & 15);
        int k = ks * 32 + (lane >> 4) * 8 + j;
        dst[i] = t[n][k];
    }
}

// ---------- edge bucketing by dst: hist, 2-level scan, scatter ----------------
__global__ void k_ehist(const int* __restrict__ edst, int* __restrict__ hist, int E) {
    int e = blockIdx.x * blockDim.x + threadIdx.x;
    if (e < E) atomicAdd(&hist[edst[e]], 1);
}
__global__ void k_scan1(const int* __restrict__ hist, int* __restrict__ blocksum, int N) {
    __shared__ int ps[256];
    int t = threadIdx.x;
    int base = blockIdx.x * 1024 + t * 4;
    int s = 0;
    #pragma unroll
    for (int k = 0; k < 4; ++k) { int i = base + k; if (i < N) s += hist[i]; }
    ps[t] = s;
    __syncthreads();
    if (t == 0) {
        int tot = 0;
        for (int i = 0; i < 256; ++i) tot += ps[i];
        blocksum[blockIdx.x] = tot;
    }
}
__global__ void k_scan2(int* __restrict__ blocksum, int* __restrict__ offs, int B, int N) {
    if (threadIdx.x == 0) {
        int o = 0;
        for (int b = 0; b < B; ++b) { int c = blocksum[b]; blocksum[b] = o; o += c; }
        offs[N] = o;
    }
}
__global__ void k_scan3(const int* __restrict__ hist, const int* __restrict__ blockoff,
                        int* __restrict__ offs, int* __restrict__ cursor, int N) {
    __shared__ int ps[256];
    int t = threadIdx.x;
    int base = blockIdx.x * 1024 + t * 4;
    int s = 0;
    #pragma unroll
    for (int k = 0; k < 4; ++k) { int i = base + k; if (i < N) s += hist[i]; }
    int mysum = s;
    ps[t] = s;
    __syncthreads();
    for (int off = 1; off < 256; off <<= 1) {
        int v = (t >= off) ? ps[t - off] : 0;
        __syncthreads();
        ps[t] += v;
        __syncthreads();
    }
    int run = ps[t] - mysum + blockoff[blockIdx.x];
    #pragma unroll
    for (int k = 0; k < 4; ++k) {
        int i = base + k;
        if (i < N) { offs[i] = run; cursor[i] = run; run += hist[i]; }
    }
}
__global__ void k_escatter(const int* __restrict__ edst, const int* __restrict__ esrc,
                           const int* __restrict__ etyp, int* __restrict__ cursor,
                           uint* __restrict__ epack, int E) {
    int e = blockIdx.x * blockDim.x + threadIdx.x;
    if (e < E) {
        int p = atomicAdd(&cursor[edst[e]], 1);
        epack[p] = ((uint)etyp[e] << 28) | (uint)esrc[e];
    }
}

// ---------- K3: z[v][r] = sum of y[src] over edges (dst=v, type=r) ------------
// one wave per dst; NAMED register accumulators + wave-uniform switch (no
// dynamic indexing -> no alloca-to-LDS promotion); 4 loads in flight per step.
__global__ void k_zagg(const ushort* __restrict__ ybuf, const int* __restrict__ offs,
                       const uint* __restrict__ epack, ushort* __restrict__ zbuf, int N) {
    int wave = threadIdx.x >> 6;
    int l = threadIdx.x & 63;
    int v = blockIdx.x * 4 + wave;
    if (v >= N) return;
    float2 a0 = {0.f,0.f}, a1 = {0.f,0.f}, a2 = {0.f,0.f}, a3 = {0.f,0.f};
    float2 a4 = {0.f,0.f}, a5 = {0.f,0.f}, a6 = {0.f,0.f}, a7 = {0.f,0.f};
    const uint* yb = (const uint*)ybuf;
    int j = offs[v], e1 = offs[v + 1];

#define ZACC(P, U) do {                                                   \
        float lo = bf_lo(U), hi = bf_hi(U);                               \
        switch ((P) >> 28) {                                              \
            case 0: a0.x += lo; a0.y += hi; break;                        \
            case 1: a1.x += lo; a1.y += hi; break;                        \
            case 2: a2.x += lo; a2.y += hi; break;                        \
            case 3: a3.x += lo; a3.y += hi; break;                        \
            case 4: a4.x += lo; a4.y += hi; break;                        \
            case 5: a5.x += lo; a5.y += hi; break;                        \
            case 6: a6.x += lo; a6.y += hi; break;                        \
            default: a7.x += lo; a7.y += hi; break;                       \
        }                                                                 \
    } while (0)

    while (j < e1) {
        int chunk = min(64, e1 - j);
        uint pl = (j + l < e1) ? epack[j + l] : 0;
        int i = 0;
        for (; i + 3 < chunk; i += 4) {
            uint p0 = __shfl(pl, i, 64);
            uint p1 = __shfl(pl, i + 1, 64);
            uint p2 = __shfl(pl, i + 2, 64);
            uint p3 = __shfl(pl, i + 3, 64);
            uint u0 = yb[(size_t)(p0 & 0x0FFFFFFFu) * 64 + l];
            uint u1 = yb[(size_t)(p1 & 0x0FFFFFFFu) * 64 + l];
            uint u2 = yb[(size_t)(p2 & 0x0FFFFFFFu) * 64 + l];
            uint u3 = yb[(size_t)(p3 & 0x0FFFFFFFu) * 64 + l];
            ZACC(p0, u0); ZACC(p1, u1); ZACC(p2, u2); ZACC(p3, u3);
        }
        for (; i < chunk; ++i) {
            uint p = __shfl(pl, i, 64);
            uint u = yb[(size_t)(p & 0x0FFFFFFFu) * 64 + l];
            ZACC(p, u);
        }
        j += chunk;
    }
#undef ZACC
    uint* zrow = (uint*)(zbuf + (size_t)v * 1024);
    zrow[0 * 64 + l] = ((uint)f2bf(a0.y) << 16) | f2bf(a0.x);
    zrow[1 * 64 + l] = ((uint)f2bf(a1.y) << 16) | f2bf(a1.x);
    zrow[2 * 64 + l] = ((uint)f2bf(a2.y) << 16) | f2bf(a2.x);
    zrow[3 * 64 + l] = ((uint)f2bf(a3.y) << 16) | f2bf(a3.x);
    zrow[4 * 64 + l] = ((uint)f2bf(a4.y) << 16) | f2bf(a4.x);
    zrow[5 * 64 + l] = ((uint)f2bf(a5.y) << 16) | f2bf(a5.x);
    zrow[6 * 64 + l] = ((uint)f2bf(a6.y) << 16) | f2bf(a6.x);
    zrow[7 * 64 + l] = ((uint)f2bf(a7.y) << 16) | f2bf(a7.x);
}

// ---------- K4: agg = [y|z] @ [Wroot;Wrel] (K=1152) + x, fused LN2+ReLU -------
// grid ceil(N/64), block 256 (4 waves x 16 rows). W staged in LDS (frag order).
// Writes x2p/y2p at PERMUTED slot pos[row] so k_mlp reads sequentially.
__launch_bounds__(256)
__global__ void k_gemm2(const ushort* __restrict__ ybuf, const ushort* __restrict__ zbuf,
                        const ushort* __restrict__ Wt, const float* __restrict__ x,
                        const int* __restrict__ ntp, const int* __restrict__ pos,
                        const float* __restrict__ gamma, const float* __restrict__ beta,
                        float* __restrict__ x2p, ushort* __restrict__ y2p, int N) {
    __shared__ ushort wsm[16384];                       // 32 KB
    int tid = threadIdx.x;
    int wave = tid >> 6, lane = tid & 63;
    int quad = lane >> 4, l15 = lane & 15;
    int base = blockIdx.x * 64 + wave * 16;
    int arow = min(base + l15, N - 1);
    const ushort* yrow = ybuf + (size_t)arow * 128;
    const ushort* zrow = zbuf + (size_t)arow * 1024;

    float4v acc[8];
    #pragma unroll
    for (int nt = 0; nt < 8; ++nt) acc[nt] = (float4v){0.f, 0.f, 0.f, 0.f};

    for (int mat = 0; mat < 9; ++mat) {
        __syncthreads();                                // protect wsm overwrite
        const ushort* wsrc = Wt + (size_t)mat * 16384;
        #pragma unroll
        for (int jj = 0; jj < 8; ++jj)
            *(uint4*)(wsm + jj * 2048 + tid * 8) = *(const uint4*)(wsrc + jj * 2048 + tid * 8);
        __syncthreads();
        const ushort* ap = (mat == 0) ? yrow : zrow + (mat - 1) * 128;
        short8 a[4];
        #pragma unroll
        for (int ks = 0; ks < 4; ++ks) a[ks] = *(const short8*)(ap + ks * 32 + quad * 8);
        #pragma unroll
        for (int nt = 0; nt < 8; ++nt) {
            #pragma unroll
            for (int ks = 0; ks < 4; ++ks) {
                short8 b = *(const short8*)(wsm + (((nt * 4 + ks) * 64 + lane) << 3));
                acc[nt] = __builtin_amdgcn_mfma_f32_16x16x32_bf16(a[ks], b, acc[nt], 0, 0, 0);
            }
        }
    }

    // epilogue: x2 = x + acc; LN2 + ReLU -> y2 (stored at permuted slots)
    float s[4] = {0.f, 0.f, 0.f, 0.f}, s2[4] = {0.f, 0.f, 0.f, 0.f};
    #pragma unroll
    for (int nt = 0; nt < 8; ++nt) {
        int col = nt * 16 + l15;
        #pragma unroll
        for (int r = 0; r < 4; ++r) {
            int row = base + quad * 4 + r;
            float xv = (row < N) ? x[(size_t)row * D + col] : 0.f;
            float t = acc[nt][r] + xv;
            acc[nt][r] = t;
            s[r] += t; s2[r] += t * t;
        }
    }
    #pragma unroll
    for (int r = 0; r < 4; ++r) {
        #pragma unroll
        for (int o = 1; o < 16; o <<= 1) {
            s[r]  += __shfl_xor(s[r],  o, 64);
            s2[r] += __shfl_xor(s2[r], o, 64);
        }
    }
    #pragma unroll
    for (int r = 0; r < 4; ++r) {
        int row = base + quad * 4 + r;
        int rc = min(row, N - 1);
        int t = ntp[rc];
        int pp = pos[rc];
        float mu  = s[r] * (1.0f / D);
        float var = s2[r] * (1.0f / D) - mu * mu;
        float inv = rsqrtf(var + EPS);
        #pragma unroll
        for (int nt = 0; nt < 8; ++nt) {
            int col = nt * 16 + l15;
            float xx = acc[nt][r];
            float yn = fmaxf((xx - mu) * inv * gamma[t * D + col] + beta[t * D + col], 0.f);
            if (row < N) {
                x2p[(size_t)pp * D + col] = xx;
                y2p[(size_t)pp * D + col] = f2bf(yn);
            }
        }
    }
}

// ---------- node-type bucketing (64-aligned) ----------------------------------
__global__ void k_nhist(const int* __restrict__ ntp, int* __restrict__ small, int N) {
    __shared__ int c[4];
    if (threadIdx.x < 4) c[threadIdx.x] = 0;
    __syncthreads();
    int n = blockIdx.x * blockDim.x + threadIdx.x;
    if (n < N) atomicAdd(&c[ntp[n]], 1);
    __syncthreads();
    if (threadIdx.x < 4 && c[threadIdx.x]) atomicAdd(&small[threadIdx.x], c[threadIdx.x]);
}
__global__ void k_prep(int* __restrict__ small, int gridMlp) {
    __shared__ int st[5];
    if (threadIdx.x == 0) {
        int o = 0;
        for (int t = 0; t < 4; ++t) {
            small[8 + t] = o;
            st[t] = o;
            o += (small[t] + 63) & ~63;
        }
        small[12] = o;
        st[4] = o;
    }
    __syncthreads();
    int* tob = small + 16;
    for (int b = threadIdx.x; b < gridMlp; b += blockDim.x) {
        int b64 = b * 64;
        int t = -1;
        for (int i = 0; i < 4; ++i)
            if (b64 >= st[i] && b64 < st[i + 1]) t = i;
        tob[b] = t;
    }
}
// block-aggregated ranks; also emits pos[n] (inverse permutation)
__global__ void k_nscatter(const int* __restrict__ ntp, int* __restrict__ small,
                           int* __restrict__ perm_pad, int* __restrict__ pos, int N) {
    __shared__ int cnt[4], base[4];
    int tid = threadIdx.x;
    if (tid < 4) cnt[tid] = 0;
    __syncthreads();
    int n = blockIdx.x * blockDim.x + tid;
    int t = 0, rank = 0;
    bool valid = (n < N);
    if (valid) { t = ntp[n]; rank = atomicAdd(&cnt[t], 1); }
    __syncthreads();
    if (tid < 4) base[tid] = cnt[tid] ? atomicAdd(&small[4 + tid], cnt[tid]) : 0;
    __syncthreads();
    if (valid) {
        int p = small[8 + t] + base[t] + rank;
        perm_pad[p] = n;
        pos[n] = p;
    }
}

// ---------- K5: MLP MFMA + residual + bias; A/x2 sequential, out scattered ----
__global__ void k_mlp(const ushort* __restrict__ y2p, const float* __restrict__ x2p,
                      const int* __restrict__ perm_pad, const int* __restrict__ small,
                      const ushort* __restrict__ Wt, const float* __restrict__ bmlp,
                      float* __restrict__ out, int N) {
    int t = small[16 + blockIdx.x];
    if (t < 0) return;
    int wave = threadIdx.x >> 6;
    int lane = threadIdx.x & 63;
    int quad = lane >> 4;
    int base = blockIdx.x * 64 + wave * 16;
    short8 a[4];
    const ushort* yrow = y2p + (size_t)(base + (lane & 15)) * D + quad * 8;
    #pragma unroll
    for (int ks = 0; ks < 4; ++ks) a[ks] = *(const short8*)(yrow + ks * 32);
    int srow[4];
    #pragma unroll
    for (int r = 0; r < 4; ++r) srow[r] = perm_pad[base + quad * 4 + r];
    const ushort* Wb = Wt + (size_t)(9 + t) * D * D;
    #pragma unroll
    for (int nt = 0; nt < 8; ++nt) {
        float4v acc = {0.f, 0.f, 0.f, 0.f};
        #pragma unroll
        for (int ks = 0; ks < 4; ++ks) {
            short8 b = *(const short8*)(Wb + (((nt * 4 + ks) * 64 + lane) << 3));
            acc = __builtin_amdgcn_mfma_f32_16x16x32_bf16(a[ks], b, acc, 0, 0, 0);
        }
        int col = nt * 16 + (lane & 15);
        float bm = bmlp[t * D + col];
        #pragma unroll
        for (int r = 0; r < 4; ++r) {
            if (srow[r] >= 0)
                out[(size_t)srow[r] * D + col] =
                    x2p[(size_t)(base + quad * 4 + r) * D + col] + acc[r] + bm;
        }
    }
}

// ---------- launch ------------------------------------------------------------
extern "C" void kernel_launch(void* const* d_in, const int* in_sizes, int n_in,
                              void* d_out, int out_size, void* d_ws, size_t ws_size,
                              hipStream_t stream) {
    const float* x          = (const float*)d_in[0];
    const int*   esrc       = (const int*)d_in[1];
    const int*   edst       = (const int*)d_in[2];
    const int*   ntyp       = (const int*)d_in[3];
    const int*   etyp       = (const int*)d_in[4];
    const float* conv_gamma = (const float*)d_in[5];
    const float* conv_beta  = (const float*)d_in[6];
    const float* W_rel      = (const float*)d_in[7];
    const float* W_root     = (const float*)d_in[8];
    const float* mlp_gamma  = (const float*)d_in[9];
    const float* mlp_beta   = (const float*)d_in[10];
    const float* W_mlp      = (const float*)d_in[11];
    const float* b_mlp      = (const float*)d_in[12];
    float* out = (float*)d_out;

    int N = in_sizes[0] / D;
    int E = in_sizes[1];
    int gridMlp = (N + 252 + 63) / 64;
    int scanB = (N + 1023) / 1024;

    char* p = (char*)d_ws;
    auto take = [&p](size_t bytes) { char* q = p; p += (bytes + 255) & ~(size_t)255; return q; };
    ushort* ybuf   = (ushort*)take((size_t)N * D * 2);
    ushort* y2p    = (ushort*)take((size_t)(N + 256) * D * 2);
    ushort* zbuf   = (ushort*)take((size_t)N * 1024 * 2);
    float*  x2p    = (float*)take((size_t)(N + 256) * D * 4);
    ushort* Wt     = (ushort*)take((size_t)13 * D * D * 2);
    int*    hist   = (int*)take((size_t)N * 4);
    int*    offs   = (int*)take((size_t)(N + 1) * 4);
    int*    cursor = (int*)take((size_t)N * 4);
    uint*   epack  = (uint*)take((size_t)E * 4);
    int*    permpad= (int*)take((size_t)(N + 256) * 4);
    int*    pos    = (int*)take((size_t)N * 4);
    int*    small  = (int*)take((size_t)(16 + gridMlp) * 4);
    int*    bsum   = (int*)take((size_t)scanB * 4);

    hipMemsetAsync(hist, 0, (size_t)N * 4, stream);
    hipMemsetAsync(small, 0, 16 * 4, stream);
    hipMemsetAsync(permpad, 0xFF, (size_t)(N + 256) * 4, stream);

    k_ln1<<<(N + 3) / 4, 256, 0, stream>>>(x, ntyp, conv_gamma, conv_beta, ybuf, N);
    k_cvt<<<13, 256, 0, stream>>>(W_rel, W_root, W_mlp, Wt);

    k_ehist<<<(E + 255) / 256, 256, 0, stream>>>(edst, hist, E);
    k_scan1<<<scanB, 256, 0, stream>>>(hist, bsum, N);
    k_scan2<<<1, 64, 0, stream>>>(bsum, offs, scanB, N);
    k_scan3<<<scanB, 256, 0, stream>>>(hist, bsum, offs, cursor, N);
    k_escatter<<<(E + 255) / 256, 256, 0, stream>>>(edst, esrc, etyp, cursor, epack, E);

    k_nhist<<<(N + 255) / 256, 256, 0, stream>>>(ntyp, small, N);
    k_prep<<<1, 256, 0, stream>>>(small, gridMlp);
    k_nscatter<<<(N + 255) / 256, 256, 0, stream>>>(ntyp, small, permpad, pos, N);

    k_zagg<<<(N + 3) / 4, 256, 0, stream>>>(ybuf, offs, epack, zbuf, N);

    k_gemm2<<<(N + 63) / 64, 256, 0, stream>>>(ybuf, zbuf, Wt, x, ntyp, pos,
                                               mlp_gamma, mlp_beta, x2p, y2p, N);

    k_mlp<<<gridMlp, 256, 0, stream>>>(y2p, x2p, permpad, small, Wt, b_mlp, out, N);
}

// Round 9
// 336.171 us; speedup vs baseline: 1.2474x; 1.0044x over previous
//
#include <hip/hip_runtime.h>
#include <hip/hip_bf16.h>

#define D 128
#define EPS 1e-5f

typedef __attribute__((ext_vector_type(8))) short short8;
typedef __attribute__((ext_vector_type(4))) float float4v;

__device__ inline ushort f2bf(float f) {
    __hip_bfloat16 b = __float2bfloat16(f);
    return *reinterpret_cast<ushort*>(&b);
}
__device__ inline float bf_lo(uint u) { return __uint_as_float(u << 16); }
__device__ inline float bf_hi(uint u) { return __uint_as_float(u & 0xffff0000u); }

// ---------- K1: LN1 + ReLU, fp32 in -> bf16 out. One wave per node. ----------
__global__ void k_ln1(const float* __restrict__ x, const int* __restrict__ ntp,
                      const float* __restrict__ gamma, const float* __restrict__ beta,
                      ushort* __restrict__ y, int N) {
    int n = blockIdx.x * 4 + (threadIdx.x >> 6);
    if (n >= N) return;
    int l = threadIdx.x & 63;
    float2 v = *(const float2*)(x + (size_t)n * D + 2 * l);
    float s = v.x + v.y, s2 = v.x * v.x + v.y * v.y;
    #pragma unroll
    for (int o = 32; o; o >>= 1) { s += __shfl_xor(s, o, 64); s2 += __shfl_xor(s2, o, 64); }
    float mu = s * (1.0f / D);
    float var = s2 * (1.0f / D) - mu * mu;
    float inv = rsqrtf(var + EPS);
    int t = ntp[n];
    float2 g = *(const float2*)(gamma + t * D + 2 * l);
    float2 b = *(const float2*)(beta + t * D + 2 * l);
    float a0 = fmaxf((v.x - mu) * inv * g.x + b.x, 0.0f);
    float a1 = fmaxf((v.y - mu) * inv * g.y + b.y, 0.0f);
    ((uint*)(y + (size_t)n * D))[l] = ((uint)f2bf(a1) << 16) | f2bf(a0);
}

// ---------- K2: weights -> bf16 in MFMA B-FRAGMENT order ----------------------
// m==0: W_root, 1..8: W_rel[m-1], 9..12: W_mlp[m-9].
__global__ void k_cvt(const float* __restrict__ Wrel, const float* __restrict__ Wroot,
                      const float* __restrict__ Wmlp, ushort* __restrict__ Wt) {
    __shared__ ushort t[128][136];
    int m = blockIdx.x;
    const float* src = (m == 0) ? Wroot
                     : (m <= 8) ? Wrel + (size_t)(m - 1) * D * D
                                : Wmlp + (size_t)(m - 9) * D * D;
    for (int i = threadIdx.x; i < D * D; i += 256) {
        int k = i >> 7, n = i & 127;
        t[n][k] = f2bf(src[i]);
    }
    __syncthreads();
    ushort* dst = Wt + (size_t)m * D * D;
    for (int i = threadIdx.x; i < D * D; i += 256) {
        int frag = i >> 9;            // 0..31  (nt*4+ks)
        int lane = (i >> 3) & 63;
        int j = i & 7;
        int nt = frag >> 2, ks = frag & 3;
        int n = nt * 16 + (lane & 15);
        int k = ks * 32 + (lane >> 4) * 8 + j;
        dst[i] = t[n][k];
    }
}

// ---------- edge bucketing by dst: hist, 2-level scan, scatter ----------------
// hist/cursor are PADDED: one counter per 64B line (stride 16 ints) to kill
// same-line atomic serialization; 4 edges/thread for 4 independent chains.
__global__ void k_ehist(const int* __restrict__ edst, int* __restrict__ hist, int E) {
    int e0 = (blockIdx.x * blockDim.x + threadIdx.x) * 4;
    if (e0 + 3 < E) {
        int4 d = *(const int4*)(edst + e0);
        atomicAdd(&hist[d.x << 4], 1);
        atomicAdd(&hist[d.y << 4], 1);
        atomicAdd(&hist[d.z << 4], 1);
        atomicAdd(&hist[d.w << 4], 1);
    } else {
        for (int e = e0; e < E; ++e) atomicAdd(&hist[edst[e] << 4], 1);
    }
}
__global__ void k_scan1(const int* __restrict__ hist, int* __restrict__ blocksum, int N) {
    __shared__ int ps[256];
    int t = threadIdx.x;
    int base = blockIdx.x * 1024 + t * 4;
    int s = 0;
    #pragma unroll
    for (int k = 0; k < 4; ++k) { int i = base + k; if (i < N) s += hist[i << 4]; }
    ps[t] = s;
    __syncthreads();
    if (t == 0) {
        int tot = 0;
        for (int i = 0; i < 256; ++i) tot += ps[i];
        blocksum[blockIdx.x] = tot;
    }
}
__global__ void k_scan2(int* __restrict__ blocksum, int* __restrict__ offs, int B, int N) {
    if (threadIdx.x == 0) {
        int o = 0;
        for (int b = 0; b < B; ++b) { int c = blocksum[b]; blocksum[b] = o; o += c; }
        offs[N] = o;
    }
}
__global__ void k_scan3(const int* __restrict__ hist, const int* __restrict__ blockoff,
                        int* __restrict__ offs, int* __restrict__ cursor, int N) {
    __shared__ int ps[256];
    int t = threadIdx.x;
    int base = blockIdx.x * 1024 + t * 4;
    int s = 0;
    #pragma unroll
    for (int k = 0; k < 4; ++k) { int i = base + k; if (i < N) s += hist[i << 4]; }
    int mysum = s;
    ps[t] = s;
    __syncthreads();
    for (int off = 1; off < 256; off <<= 1) {
        int v = (t >= off) ? ps[t - off] : 0;
        __syncthreads();
        ps[t] += v;
        __syncthreads();
    }
    int run = ps[t] - mysum + blockoff[blockIdx.x];
    #pragma unroll
    for (int k = 0; k < 4; ++k) {
        int i = base + k;
        if (i < N) { offs[i] = run; cursor[i << 4] = run; run += hist[i << 4]; }
    }
}
__global__ void k_escatter(const int* __restrict__ edst, const int* __restrict__ esrc,
                           const int* __restrict__ etyp, int* __restrict__ cursor,
                           uint* __restrict__ epack, int E) {
    int e0 = (blockIdx.x * blockDim.x + threadIdx.x) * 4;
    if (e0 + 3 < E) {
        int4 d = *(const int4*)(edst + e0);
        int4 s = *(const int4*)(esrc + e0);
        int4 t = *(const int4*)(etyp + e0);
        int p0 = atomicAdd(&cursor[d.x << 4], 1);
        int p1 = atomicAdd(&cursor[d.y << 4], 1);
        int p2 = atomicAdd(&cursor[d.z << 4], 1);
        int p3 = atomicAdd(&cursor[d.w << 4], 1);
        epack[p0] = ((uint)t.x << 28) | (uint)s.x;
        epack[p1] = ((uint)t.y << 28) | (uint)s.y;
        epack[p2] = ((uint)t.z << 28) | (uint)s.z;
        epack[p3] = ((uint)t.w << 28) | (uint)s.w;
    } else {
        for (int e = e0; e < E; ++e) {
            int p = atomicAdd(&cursor[edst[e] << 4], 1);
            epack[p] = ((uint)etyp[e] << 28) | (uint)esrc[e];
        }
    }
}

// ---------- K3: z[v][r] = sum of y[src] over edges (dst=v, type=r) ------------
// one wave per dst; NAMED register accumulators + wave-uniform switch (no
// dynamic indexing -> no alloca-to-LDS promotion); 4 loads in flight per step.
__global__ void k_zagg(const ushort* __restrict__ ybuf, const int* __restrict__ offs,
                       const uint* __restrict__ epack, ushort* __restrict__ zbuf, int N) {
    int wave = threadIdx.x >> 6;
    int l = threadIdx.x & 63;
    int v = blockIdx.x * 4 + wave;
    if (v >= N) return;
    float2 a0 = {0.f,0.f}, a1 = {0.f,0.f}, a2 = {0.f,0.f}, a3 = {0.f,0.f};
    float2 a4 = {0.f,0.f}, a5 = {0.f,0.f}, a6 = {0.f,0.f}, a7 = {0.f,0.f};
    const uint* yb = (const uint*)ybuf;
    int j = offs[v], e1 = offs[v + 1];

#define ZACC(P, U) do {                                                   \
        float lo = bf_lo(U), hi = bf_hi(U);                               \
        switch ((P) >> 28) {                                              \
            case 0: a0.x += lo; a0.y += hi; break;                        \
            case 1: a1.x += lo; a1.y += hi; break;                        \
            case 2: a2.x += lo; a2.y += hi; break;                        \
            case 3: a3.x += lo; a3.y += hi; break;                        \
            case 4: a4.x += lo; a4.y += hi; break;                        \
            case 5: a5.x += lo; a5.y += hi; break;                        \
            case 6: a6.x += lo; a6.y += hi; break;                        \
            default: a7.x += lo; a7.y += hi; break;                       \
        }                                                                 \
    } while (0)

    while (j < e1) {
        int chunk = min(64, e1 - j);
        uint pl = (j + l < e1) ? epack[j + l] : 0;
        int i = 0;
        for (; i + 3 < chunk; i += 4) {
            uint p0 = __shfl(pl, i, 64);
            uint p1 = __shfl(pl, i + 1, 64);
            uint p2 = __shfl(pl, i + 2, 64);
            uint p3 = __shfl(pl, i + 3, 64);
            uint u0 = yb[(size_t)(p0 & 0x0FFFFFFFu) * 64 + l];
            uint u1 = yb[(size_t)(p1 & 0x0FFFFFFFu) * 64 + l];
            uint u2 = yb[(size_t)(p2 & 0x0FFFFFFFu) * 64 + l];
            uint u3 = yb[(size_t)(p3 & 0x0FFFFFFFu) * 64 + l];
            ZACC(p0, u0); ZACC(p1, u1); ZACC(p2, u2); ZACC(p3, u3);
        }
        for (; i < chunk; ++i) {
            uint p = __shfl(pl, i, 64);
            uint u = yb[(size_t)(p & 0x0FFFFFFFu) * 64 + l];
            ZACC(p, u);
        }
        j += chunk;
    }
#undef ZACC
    uint* zrow = (uint*)(zbuf + (size_t)v * 1024);
    zrow[0 * 64 + l] = ((uint)f2bf(a0.y) << 16) | f2bf(a0.x);
    zrow[1 * 64 + l] = ((uint)f2bf(a1.y) << 16) | f2bf(a1.x);
    zrow[2 * 64 + l] = ((uint)f2bf(a2.y) << 16) | f2bf(a2.x);
    zrow[3 * 64 + l] = ((uint)f2bf(a3.y) << 16) | f2bf(a3.x);
    zrow[4 * 64 + l] = ((uint)f2bf(a4.y) << 16) | f2bf(a4.x);
    zrow[5 * 64 + l] = ((uint)f2bf(a5.y) << 16) | f2bf(a5.x);
    zrow[6 * 64 + l] = ((uint)f2bf(a6.y) << 16) | f2bf(a6.x);
    zrow[7 * 64 + l] = ((uint)f2bf(a7.y) << 16) | f2bf(a7.x);
}

// ---------- K4: agg = [y|z] @ [Wroot;Wrel] (K=1152) + x, fused LN2+ReLU -------
// grid ceil(N/64), block 256 (4 waves x 16 rows). W staged in LDS (frag order).
// Writes x2p/y2p at PERMUTED slot pos[row] so k_mlp reads sequentially.
__launch_bounds__(256)
__global__ void k_gemm2(const ushort* __restrict__ ybuf, const ushort* __restrict__ zbuf,
                        const ushort* __restrict__ Wt, const float* __restrict__ x,
                        const int* __restrict__ ntp, const int* __restrict__ pos,
                        const float* __restrict__ gamma, const float* __restrict__ beta,
                        float* __restrict__ x2p, ushort* __restrict__ y2p, int N) {
    __shared__ ushort wsm[16384];                       // 32 KB
    int tid = threadIdx.x;
    int wave = tid >> 6, lane = tid & 63;
    int quad = lane >> 4, l15 = lane & 15;
    int base = blockIdx.x * 64 + wave * 16;
    int arow = min(base + l15, N - 1);
    const ushort* yrow = ybuf + (size_t)arow * 128;
    const ushort* zrow = zbuf + (size_t)arow * 1024;

    float4v acc[8];
    #pragma unroll
    for (int nt = 0; nt < 8; ++nt) acc[nt] = (float4v){0.f, 0.f, 0.f, 0.f};

    for (int mat = 0; mat < 9; ++mat) {
        __syncthreads();                                // protect wsm overwrite
        const ushort* wsrc = Wt + (size_t)mat * 16384;
        #pragma unroll
        for (int jj = 0; jj < 8; ++jj)
            *(uint4*)(wsm + jj * 2048 + tid * 8) = *(const uint4*)(wsrc + jj * 2048 + tid * 8);
        __syncthreads();
        const ushort* ap = (mat == 0) ? yrow : zrow + (mat - 1) * 128;
        short8 a[4];
        #pragma unroll
        for (int ks = 0; ks < 4; ++ks) a[ks] = *(const short8*)(ap + ks * 32 + quad * 8);
        #pragma unroll
        for (int nt = 0; nt < 8; ++nt) {
            #pragma unroll
            for (int ks = 0; ks < 4; ++ks) {
                short8 b = *(const short8*)(wsm + (((nt * 4 + ks) * 64 + lane) << 3));
                acc[nt] = __builtin_amdgcn_mfma_f32_16x16x32_bf16(a[ks], b, acc[nt], 0, 0, 0);
            }
        }
    }

    // epilogue: x2 = x + acc; LN2 + ReLU -> y2 (stored at permuted slots)
    float s[4] = {0.f, 0.f, 0.f, 0.f}, s2[4] = {0.f, 0.f, 0.f, 0.f};
    #pragma unroll
    for (int nt = 0; nt < 8; ++nt) {
        int col = nt * 16 + l15;
        #pragma unroll
        for (int r = 0; r < 4; ++r) {
            int row = base + quad * 4 + r;
            float xv = (row < N) ? x[(size_t)row * D + col] : 0.f;
            float t = acc[nt][r] + xv;
            acc[nt][r] = t;
            s[r] += t; s2[r] += t * t;
        }
    }
    #pragma unroll
    for (int r = 0; r < 4; ++r) {
        #pragma unroll
        for (int o = 1; o < 16; o <<= 1) {
            s[r]  += __shfl_xor(s[r],  o, 64);
            s2[r] += __shfl_xor(s2[r], o, 64);
        }
    }
    #pragma unroll
    for (int r = 0; r < 4; ++r) {
        int row = base + quad * 4 + r;
        int rc = min(row, N - 1);
        int t = ntp[rc];
        int pp = pos[rc];
        float mu  = s[r] * (1.0f / D);
        float var = s2[r] * (1.0f / D) - mu * mu;
        float inv = rsqrtf(var + EPS);
        #pragma unroll
        for (int nt = 0; nt < 8; ++nt) {
            int col = nt * 16 + l15;
            float xx = acc[nt][r];
            float yn = fmaxf((xx - mu) * inv * gamma[t * D + col] + beta[t * D + col], 0.f);
            if (row < N) {
                x2p[(size_t)pp * D + col] = xx;
                y2p[(size_t)pp * D + col] = f2bf(yn);
            }
        }
    }
}

// ---------- node-type bucketing (64-aligned) ----------------------------------
__global__ void k_nhist(const int* __restrict__ ntp, int* __restrict__ small, int N) {
    __shared__ int c[4];
    if (threadIdx.x < 4) c[threadIdx.x] = 0;
    __syncthreads();
    int n = blockIdx.x * blockDim.x + threadIdx.x;
    if (n < N) atomicAdd(&c[ntp[n]], 1);
    __syncthreads();
    if (threadIdx.x < 4 && c[threadIdx.x]) atomicAdd(&small[threadIdx.x], c[threadIdx.x]);
}
__global__ void k_prep(int* __restrict__ small, int gridMlp) {
    __shared__ int st[5];
    if (threadIdx.x == 0) {
        int o = 0;
        for (int t = 0; t < 4; ++t) {
            small[8 + t] = o;
            st[t] = o;
            o += (small[t] + 63) & ~63;
        }
        small[12] = o;
        st[4] = o;
    }
    __syncthreads();
    int* tob = small + 16;
    for (int b = threadIdx.x; b < gridMlp; b += blockDim.x) {
        int b64 = b * 64;
        int t = -1;
        for (int i = 0; i < 4; ++i)
            if (b64 >= st[i] && b64 < st[i + 1]) t = i;
        tob[b] = t;
    }
}
// block-aggregated ranks; also emits pos[n] (inverse permutation)
__global__ void k_nscatter(const int* __restrict__ ntp, int* __restrict__ small,
                           int* __restrict__ perm_pad, int* __restrict__ pos, int N) {
    __shared__ int cnt[4], base[4];
    int tid = threadIdx.x;
    if (tid < 4) cnt[tid] = 0;
    __syncthreads();
    int n = blockIdx.x * blockDim.x + tid;
    int t = 0, rank = 0;
    bool valid = (n < N);
    if (valid) { t = ntp[n]; rank = atomicAdd(&cnt[t], 1); }
    __syncthreads();
    if (tid < 4) base[tid] = cnt[tid] ? atomicAdd(&small[4 + tid], cnt[tid]) : 0;
    __syncthreads();
    if (valid) {
        int p = small[8 + t] + base[t] + rank;
        perm_pad[p] = n;
        pos[n] = p;
    }
}

// ---------- K5: MLP MFMA + residual + bias; A/x2 sequential, out scattered ----
__global__ void k_mlp(const ushort* __restrict__ y2p, const float* __restrict__ x2p,
                      const int* __restrict__ perm_pad, const int* __restrict__ small,
                      const ushort* __restrict__ Wt, const float* __restrict__ bmlp,
                      float* __restrict__ out, int N) {
    int t = small[16 + blockIdx.x];
    if (t < 0) return;
    int wave = threadIdx.x >> 6;
    int lane = threadIdx.x & 63;
    int quad = lane >> 4;
    int base = blockIdx.x * 64 + wave * 16;
    short8 a[4];
    const ushort* yrow = y2p + (size_t)(base + (lane & 15)) * D + quad * 8;
    #pragma unroll
    for (int ks = 0; ks < 4; ++ks) a[ks] = *(const short8*)(yrow + ks * 32);
    int srow[4];
    #pragma unroll
    for (int r = 0; r < 4; ++r) srow[r] = perm_pad[base + quad * 4 + r];
    const ushort* Wb = Wt + (size_t)(9 + t) * D * D;
    #pragma unroll
    for (int nt = 0; nt < 8; ++nt) {
        float4v acc = {0.f, 0.f, 0.f, 0.f};
        #pragma unroll
        for (int ks = 0; ks < 4; ++ks) {
            short8 b = *(const short8*)(Wb + (((nt * 4 + ks) * 64 + lane) << 3));
            acc = __builtin_amdgcn_mfma_f32_16x16x32_bf16(a[ks], b, acc, 0, 0, 0);
        }
        int col = nt * 16 + (lane & 15);
        float bm = bmlp[t * D + col];
        #pragma unroll
        for (int r = 0; r < 4; ++r) {
            if (srow[r] >= 0)
                out[(size_t)srow[r] * D + col] =
                    x2p[(size_t)(base + quad * 4 + r) * D + col] + acc[r] + bm;
        }
    }
}

// ---------- launch ------------------------------------------------------------
extern "C" void kernel_launch(void* const* d_in, const int* in_sizes, int n_in,
                              void* d_out, int out_size, void* d_ws, size_t ws_size,
                              hipStream_t stream) {
    const float* x          = (const float*)d_in[0];
    const int*   esrc       = (const int*)d_in[1];
    const int*   edst       = (const int*)d_in[2];
    const int*   ntyp       = (const int*)d_in[3];
    const int*   etyp       = (const int*)d_in[4];
    const float* conv_gamma = (const float*)d_in[5];
    const float* conv_beta  = (const float*)d_in[6];
    const float* W_rel      = (const float*)d_in[7];
    const float* W_root     = (const float*)d_in[8];
    const float* mlp_gamma  = (const float*)d_in[9];
    const float* mlp_beta   = (const float*)d_in[10];
    const float* W_mlp      = (const float*)d_in[11];
    const float* b_mlp      = (const float*)d_in[12];
    float* out = (float*)d_out;

    int N = in_sizes[0] / D;
    int E = in_sizes[1];
    int gridMlp = (N + 252 + 63) / 64;
    int scanB = (N + 1023) / 1024;

    char* p = (char*)d_ws;
    auto take = [&p](size_t bytes) { char* q = p; p += (bytes + 255) & ~(size_t)255; return q; };
    ushort* ybuf   = (ushort*)take((size_t)N * D * 2);
    ushort* y2p    = (ushort*)take((size_t)(N + 256) * D * 2);
    ushort* zbuf   = (ushort*)take((size_t)N * 1024 * 2);
    float*  x2p    = (float*)take((size_t)(N + 256) * D * 4);
    ushort* Wt     = (ushort*)take((size_t)13 * D * D * 2);
    int*    hist   = (int*)take((size_t)N * 64);       // padded: 1 counter / 64B
    int*    cursor = (int*)take((size_t)N * 64);       // padded: 1 counter / 64B
    int*    offs   = (int*)take((size_t)(N + 1) * 4);
    uint*   epack  = (uint*)take((size_t)E * 4);
    int*    permpad= (int*)take((size_t)(N + 256) * 4);
    int*    pos    = (int*)take((size_t)N * 4);
    int*    small  = (int*)take((size_t)(16 + gridMlp) * 4);
    int*    bsum   = (int*)take((size_t)scanB * 4);

    hipMemsetAsync(hist, 0, (size_t)N * 64, stream);
    hipMemsetAsync(small, 0, 16 * 4, stream);
    hipMemsetAsync(permpad, 0xFF, (size_t)(N + 256) * 4, stream);

    k_ln1<<<(N + 3) / 4, 256, 0, stream>>>(x, ntyp, conv_gamma, conv_beta, ybuf, N);
    k_cvt<<<13, 256, 0, stream>>>(W_rel, W_root, W_mlp, Wt);

    k_ehist<<<(E / 4 + 255) / 256, 256, 0, stream>>>(edst, hist, E);
    k_scan1<<<scanB, 256, 0, stream>>>(hist, bsum, N);
    k_scan2<<<1, 64, 0, stream>>>(bsum, offs, scanB, N);
    k_scan3<<<scanB, 256, 0, stream>>>(hist, bsum, offs, cursor, N);
    k_escatter<<<(E / 4 + 255) / 256, 256, 0, stream>>>(edst, esrc, etyp, cursor, epack, E);

    k_nhist<<<(N + 255) / 256, 256, 0, stream>>>(ntyp, small, N);
    k_prep<<<1, 256, 0, stream>>>(small, gridMlp);
    k_nscatter<<<(N + 255) / 256, 256, 0, stream>>>(ntyp, small, permpad, pos, N);

    k_zagg<<<(N + 3) / 4, 256, 0, stream>>>(ybuf, offs, epack, zbuf, N);

    k_gemm2<<<(N + 63) / 64, 256, 0, stream>>>(ybuf, zbuf, Wt, x, ntyp, pos,
                                               mlp_gamma, mlp_beta, x2p, y2p, N);

    k_mlp<<<gridMlp, 256, 0, stream>>>(y2p, x2p, permpad, small, Wt, b_mlp, out, N);
}

// Round 10
// 324.230 us; speedup vs baseline: 1.2933x; 1.0368x over previous
//
#include <hip/hip_runtime.h>
#include <hip/hip_bf16.h>

#define D 128
#define EPS 1e-5f

typedef __attribute__((ext_vector_type(8))) short short8;
typedef __attribute__((ext_vector_type(4))) float float4v;

__device__ inline ushort f2bf(float f) {
    __hip_bfloat16 b = __float2bfloat16(f);
    return *reinterpret_cast<ushort*>(&b);
}
__device__ inline float bf_lo(uint u) { return __uint_as_float(u << 16); }
__device__ inline float bf_hi(uint u) { return __uint_as_float(u & 0xffff0000u); }

// ---------- K1: LN1 + ReLU, fp32 in -> bf16 out. One wave per node. ----------
__global__ void k_ln1(const float* __restrict__ x, const int* __restrict__ ntp,
                      const float* __restrict__ gamma, const float* __restrict__ beta,
                      ushort* __restrict__ y, int N) {
    int n = blockIdx.x * 4 + (threadIdx.x >> 6);
    if (n >= N) return;
    int l = threadIdx.x & 63;
    float2 v = *(const float2*)(x + (size_t)n * D + 2 * l);
    float s = v.x + v.y, s2 = v.x * v.x + v.y * v.y;
    #pragma unroll
    for (int o = 32; o; o >>= 1) { s += __shfl_xor(s, o, 64); s2 += __shfl_xor(s2, o, 64); }
    float mu = s * (1.0f / D);
    float var = s2 * (1.0f / D) - mu * mu;
    float inv = rsqrtf(var + EPS);
    int t = ntp[n];
    float2 g = *(const float2*)(gamma + t * D + 2 * l);
    float2 b = *(const float2*)(beta + t * D + 2 * l);
    float a0 = fmaxf((v.x - mu) * inv * g.x + b.x, 0.0f);
    float a1 = fmaxf((v.y - mu) * inv * g.y + b.y, 0.0f);
    ((uint*)(y + (size_t)n * D))[l] = ((uint)f2bf(a1) << 16) | f2bf(a0);
}

// ---------- K2: weights -> bf16 in MFMA B-FRAGMENT order ----------------------
// m==0: W_root, 1..8: W_rel[m-1], 9..12: W_mlp[m-9].
__global__ void k_cvt(const float* __restrict__ Wrel, const float* __restrict__ Wroot,
                      const float* __restrict__ Wmlp, ushort* __restrict__ Wt) {
    __shared__ ushort t[128][136];
    int m = blockIdx.x;
    const float* src = (m == 0) ? Wroot
                     : (m <= 8) ? Wrel + (size_t)(m - 1) * D * D
                                : Wmlp + (size_t)(m - 9) * D * D;
    for (int i = threadIdx.x; i < D * D; i += 256) {
        int k = i >> 7, n = i & 127;
        t[n][k] = f2bf(src[i]);
    }
    __syncthreads();
    ushort* dst = Wt + (size_t)m * D * D;
    for (int i = threadIdx.x; i < D * D; i += 256) {
        int frag = i >> 9;            // 0..31  (nt*4+ks)
        int lane = (i >> 3) & 63;
        int j = i & 7;
        int nt = frag >> 2, ks = frag & 3;
        int n = nt * 16 + (lane & 15);
        int k = ks * 32 + (lane >> 4) * 8 + j;
        dst[i] = t[n][k];
    }
}

// ---------- edge bucketing by dst: hist, 2-level scan, scatter ----------------
// hist/cursor PADDED: one counter per 64B line (stride-16 ints); 1 edge/thread
// for max parallelism (R8) + padding (R9) -- decoupled this time.
__global__ void k_ehist(const int* __restrict__ edst, int* __restrict__ hist, int E) {
    int e = blockIdx.x * blockDim.x + threadIdx.x;
    if (e < E) atomicAdd(&hist[edst[e] << 4], 1);
}
__global__ void k_scan1(const int* __restrict__ hist, int* __restrict__ blocksum, int N) {
    __shared__ int ps[256];
    int t = threadIdx.x;
    int base = blockIdx.x * 1024 + t * 4;
    int s = 0;
    #pragma unroll
    for (int k = 0; k < 4; ++k) { int i = base + k; if (i < N) s += hist[i << 4]; }
    ps[t] = s;
    __syncthreads();
    if (t == 0) {
        int tot = 0;
        for (int i = 0; i < 256; ++i) tot += ps[i];
        blocksum[blockIdx.x] = tot;
    }
}
__global__ void k_scan2(int* __restrict__ blocksum, int* __restrict__ offs, int B, int N) {
    if (threadIdx.x == 0) {
        int o = 0;
        for (int b = 0; b < B; ++b) { int c = blocksum[b]; blocksum[b] = o; o += c; }
        offs[N] = o;
    }
}
__global__ void k_scan3(const int* __restrict__ hist, const int* __restrict__ blockoff,
                        int* __restrict__ offs, int* __restrict__ cursor, int N) {
    __shared__ int ps[256];
    int t = threadIdx.x;
    int base = blockIdx.x * 1024 + t * 4;
    int s = 0;
    #pragma unroll
    for (int k = 0; k < 4; ++k) { int i = base + k; if (i < N) s += hist[i << 4]; }
    int mysum = s;
    ps[t] = s;
    __syncthreads();
    for (int off = 1; off < 256; off <<= 1) {
        int v = (t >= off) ? ps[t - off] : 0;
        __syncthreads();
        ps[t] += v;
        __syncthreads();
    }
    int run = ps[t] - mysum + blockoff[blockIdx.x];
    #pragma unroll
    for (int k = 0; k < 4; ++k) {
        int i = base + k;
        if (i < N) { offs[i] = run; cursor[i << 4] = run; run += hist[i << 4]; }
    }
}
__global__ void k_escatter(const int* __restrict__ edst, const int* __restrict__ esrc,
                           const int* __restrict__ etyp, int* __restrict__ cursor,
                           uint* __restrict__ epack, int E) {
    int e = blockIdx.x * blockDim.x + threadIdx.x;
    if (e < E) {
        int p = atomicAdd(&cursor[edst[e] << 4], 1);
        epack[p] = ((uint)etyp[e] << 28) | (uint)esrc[e];
    }
}

// ---------- K3: z[v][r] = sum of y[src] over edges (dst=v, type=r) ------------
// one wave per dst; NAMED register accumulators + wave-uniform switch; 4 loads
// in flight per step.
__global__ void k_zagg(const ushort* __restrict__ ybuf, const int* __restrict__ offs,
                       const uint* __restrict__ epack, ushort* __restrict__ zbuf, int N) {
    int wave = threadIdx.x >> 6;
    int l = threadIdx.x & 63;
    int v = blockIdx.x * 4 + wave;
    if (v >= N) return;
    float2 a0 = {0.f,0.f}, a1 = {0.f,0.f}, a2 = {0.f,0.f}, a3 = {0.f,0.f};
    float2 a4 = {0.f,0.f}, a5 = {0.f,0.f}, a6 = {0.f,0.f}, a7 = {0.f,0.f};
    const uint* yb = (const uint*)ybuf;
    int j = offs[v], e1 = offs[v + 1];

#define ZACC(P, U) do {                                                   \
        float lo = bf_lo(U), hi = bf_hi(U);                               \
        switch ((P) >> 28) {                                              \
            case 0: a0.x += lo; a0.y += hi; break;                        \
            case 1: a1.x += lo; a1.y += hi; break;                        \
            case 2: a2.x += lo; a2.y += hi; break;                        \
            case 3: a3.x += lo; a3.y += hi; break;                        \
            case 4: a4.x += lo; a4.y += hi; break;                        \
            case 5: a5.x += lo; a5.y += hi; break;                        \
            case 6: a6.x += lo; a6.y += hi; break;                        \
            default: a7.x += lo; a7.y += hi; break;                       \
        }                                                                 \
    } while (0)

    while (j < e1) {
        int chunk = min(64, e1 - j);
        uint pl = (j + l < e1) ? epack[j + l] : 0;
        int i = 0;
        for (; i + 3 < chunk; i += 4) {
            uint p0 = __shfl(pl, i, 64);
            uint p1 = __shfl(pl, i + 1, 64);
            uint p2 = __shfl(pl, i + 2, 64);
            uint p3 = __shfl(pl, i + 3, 64);
            uint u0 = yb[(size_t)(p0 & 0x0FFFFFFFu) * 64 + l];
            uint u1 = yb[(size_t)(p1 & 0x0FFFFFFFu) * 64 + l];
            uint u2 = yb[(size_t)(p2 & 0x0FFFFFFFu) * 64 + l];
            uint u3 = yb[(size_t)(p3 & 0x0FFFFFFFu) * 64 + l];
            ZACC(p0, u0); ZACC(p1, u1); ZACC(p2, u2); ZACC(p3, u3);
        }
        for (; i < chunk; ++i) {
            uint p = __shfl(pl, i, 64);
            uint u = yb[(size_t)(p & 0x0FFFFFFFu) * 64 + l];
            ZACC(p, u);
        }
        j += chunk;
    }
#undef ZACC
    uint* zrow = (uint*)(zbuf + (size_t)v * 1024);
    zrow[0 * 64 + l] = ((uint)f2bf(a0.y) << 16) | f2bf(a0.x);
    zrow[1 * 64 + l] = ((uint)f2bf(a1.y) << 16) | f2bf(a1.x);
    zrow[2 * 64 + l] = ((uint)f2bf(a2.y) << 16) | f2bf(a2.x);
    zrow[3 * 64 + l] = ((uint)f2bf(a3.y) << 16) | f2bf(a3.x);
    zrow[4 * 64 + l] = ((uint)f2bf(a4.y) << 16) | f2bf(a4.x);
    zrow[5 * 64 + l] = ((uint)f2bf(a5.y) << 16) | f2bf(a5.x);
    zrow[6 * 64 + l] = ((uint)f2bf(a6.y) << 16) | f2bf(a6.x);
    zrow[7 * 64 + l] = ((uint)f2bf(a7.y) << 16) | f2bf(a7.x);
}

// ---------- K4: agg = [y|z] @ [Wroot;Wrel] (K=1152) + x, fused LN2+ReLU -------
// grid ceil(N/64), block 256 (4 waves x 16 rows). W staged in LDS (frag order).
__launch_bounds__(256)
__global__ void k_gemm2(const ushort* __restrict__ ybuf, const ushort* __restrict__ zbuf,
                        const ushort* __restrict__ Wt, const float* __restrict__ x,
                        const int* __restrict__ ntp,
                        const float* __restrict__ gamma, const float* __restrict__ beta,
                        float* __restrict__ x2, ushort* __restrict__ y2, int N) {
    __shared__ ushort wsm[16384];                       // 32 KB
    int tid = threadIdx.x;
    int wave = tid >> 6, lane = tid & 63;
    int quad = lane >> 4, l15 = lane & 15;
    int base = blockIdx.x * 64 + wave * 16;
    int arow = min(base + l15, N - 1);
    const ushort* yrow = ybuf + (size_t)arow * 128;
    const ushort* zrow = zbuf + (size_t)arow * 1024;

    float4v acc[8];
    #pragma unroll
    for (int nt = 0; nt < 8; ++nt) acc[nt] = (float4v){0.f, 0.f, 0.f, 0.f};

    for (int mat = 0; mat < 9; ++mat) {
        __syncthreads();                                // protect wsm overwrite
        const ushort* wsrc = Wt + (size_t)mat * 16384;
        #pragma unroll
        for (int jj = 0; jj < 8; ++jj)
            *(uint4*)(wsm + jj * 2048 + tid * 8) = *(const uint4*)(wsrc + jj * 2048 + tid * 8);
        __syncthreads();
        const ushort* ap = (mat == 0) ? yrow : zrow + (mat - 1) * 128;
        short8 a[4];
        #pragma unroll
        for (int ks = 0; ks < 4; ++ks) a[ks] = *(const short8*)(ap + ks * 32 + quad * 8);
        #pragma unroll
        for (int nt = 0; nt < 8; ++nt) {
            #pragma unroll
            for (int ks = 0; ks < 4; ++ks) {
                short8 b = *(const short8*)(wsm + (((nt * 4 + ks) * 64 + lane) << 3));
                acc[nt] = __builtin_amdgcn_mfma_f32_16x16x32_bf16(a[ks], b, acc[nt], 0, 0, 0);
            }
        }
    }

    // epilogue: x2 = x + acc; LN2 + ReLU -> y2
    float s[4] = {0.f, 0.f, 0.f, 0.f}, s2[4] = {0.f, 0.f, 0.f, 0.f};
    #pragma unroll
    for (int nt = 0; nt < 8; ++nt) {
        int col = nt * 16 + l15;
        #pragma unroll
        for (int r = 0; r < 4; ++r) {
            int row = base + quad * 4 + r;
            float xv = (row < N) ? x[(size_t)row * D + col] : 0.f;
            float t = acc[nt][r] + xv;
            acc[nt][r] = t;
            s[r] += t; s2[r] += t * t;
        }
    }
    #pragma unroll
    for (int r = 0; r < 4; ++r) {
        #pragma unroll
        for (int o = 1; o < 16; o <<= 1) {
            s[r]  += __shfl_xor(s[r],  o, 64);
            s2[r] += __shfl_xor(s2[r], o, 64);
        }
    }
    #pragma unroll
    for (int r = 0; r < 4; ++r) {
        int row = base + quad * 4 + r;
        int rc = min(row, N - 1);
        int t = ntp[rc];
        float mu  = s[r] * (1.0f / D);
        float var = s2[r] * (1.0f / D) - mu * mu;
        float inv = rsqrtf(var + EPS);
        #pragma unroll
        for (int nt = 0; nt < 8; ++nt) {
            int col = nt * 16 + l15;
            float xx = acc[nt][r];
            float yn = fmaxf((xx - mu) * inv * gamma[t * D + col] + beta[t * D + col], 0.f);
            if (row < N) {
                x2[(size_t)row * D + col] = xx;
                y2[(size_t)row * D + col] = f2bf(yn);
            }
        }
    }
}

// ---------- K5: MLP for ALL 4 types + per-row select + residual + bias --------
// No node bucketing needed: MLP FLOPs are trivial, so compute 4 variants and
// select per row (named accumulators + ternaries; NO dynamic reg indexing).
__global__ void k_mlp(const ushort* __restrict__ y2, const float* __restrict__ x2,
                      const int* __restrict__ ntp,
                      const ushort* __restrict__ Wt, const float* __restrict__ bmlp,
                      float* __restrict__ out, int N) {
    int wave = threadIdx.x >> 6;
    int lane = threadIdx.x & 63;
    int quad = lane >> 4, l15 = lane & 15;
    int base = blockIdx.x * 64 + wave * 16;
    int arow = min(base + l15, N - 1);
    short8 a[4];
    const ushort* yrow = y2 + (size_t)arow * D + quad * 8;
    #pragma unroll
    for (int ks = 0; ks < 4; ++ks) a[ks] = *(const short8*)(yrow + ks * 32);
    int ty[4];
    #pragma unroll
    for (int r = 0; r < 4; ++r) ty[r] = ntp[min(base + quad * 4 + r, N - 1)];
    const ushort* W0 = Wt + (size_t)9  * D * D;
    const ushort* W1 = Wt + (size_t)10 * D * D;
    const ushort* W2 = Wt + (size_t)11 * D * D;
    const ushort* W3 = Wt + (size_t)12 * D * D;
    #pragma unroll
    for (int nt = 0; nt < 8; ++nt) {
        float4v c0 = {0.f,0.f,0.f,0.f}, c1 = {0.f,0.f,0.f,0.f};
        float4v c2 = {0.f,0.f,0.f,0.f}, c3 = {0.f,0.f,0.f,0.f};
        #pragma unroll
        for (int ks = 0; ks < 4; ++ks) {
            int fo = ((nt * 4 + ks) * 64 + lane) << 3;
            short8 b0 = *(const short8*)(W0 + fo);
            short8 b1 = *(const short8*)(W1 + fo);
            short8 b2 = *(const short8*)(W2 + fo);
            short8 b3 = *(const short8*)(W3 + fo);
            c0 = __builtin_amdgcn_mfma_f32_16x16x32_bf16(a[ks], b0, c0, 0, 0, 0);
            c1 = __builtin_amdgcn_mfma_f32_16x16x32_bf16(a[ks], b1, c1, 0, 0, 0);
            c2 = __builtin_amdgcn_mfma_f32_16x16x32_bf16(a[ks], b2, c2, 0, 0, 0);
            c3 = __builtin_amdgcn_mfma_f32_16x16x32_bf16(a[ks], b3, c3, 0, 0, 0);
        }
        int col = nt * 16 + l15;
        #pragma unroll
        for (int r = 0; r < 4; ++r) {
            int row = base + quad * 4 + r;
            if (row < N) {
                int t = ty[r];
                float v = (t == 0) ? c0[r] : (t == 1) ? c1[r] : (t == 2) ? c2[r] : c3[r];
                out[(size_t)row * D + col] =
                    x2[(size_t)row * D + col] + v + bmlp[t * D + col];
            }
        }
    }
}

// ---------- launch ------------------------------------------------------------
extern "C" void kernel_launch(void* const* d_in, const int* in_sizes, int n_in,
                              void* d_out, int out_size, void* d_ws, size_t ws_size,
                              hipStream_t stream) {
    const float* x          = (const float*)d_in[0];
    const int*   esrc       = (const int*)d_in[1];
    const int*   edst       = (const int*)d_in[2];
    const int*   ntyp       = (const int*)d_in[3];
    const int*   etyp       = (const int*)d_in[4];
    const float* conv_gamma = (const float*)d_in[5];
    const float* conv_beta  = (const float*)d_in[6];
    const float* W_rel      = (const float*)d_in[7];
    const float* W_root     = (const float*)d_in[8];
    const float* mlp_gamma  = (const float*)d_in[9];
    const float* mlp_beta   = (const float*)d_in[10];
    const float* W_mlp      = (const float*)d_in[11];
    const float* b_mlp      = (const float*)d_in[12];
    float* out = (float*)d_out;

    int N = in_sizes[0] / D;
    int E = in_sizes[1];
    int scanB = (N + 1023) / 1024;

    char* p = (char*)d_ws;
    auto take = [&p](size_t bytes) { char* q = p; p += (bytes + 255) & ~(size_t)255; return q; };
    ushort* ybuf   = (ushort*)take((size_t)N * D * 2);
    ushort* y2     = (ushort*)take((size_t)N * D * 2);
    ushort* zbuf   = (ushort*)take((size_t)N * 1024 * 2);
    float*  x2     = (float*)take((size_t)N * D * 4);
    ushort* Wt     = (ushort*)take((size_t)13 * D * D * 2);
    int*    hist   = (int*)take((size_t)N * 64);       // padded: 1 counter / 64B
    int*    cursor = (int*)take((size_t)N * 64);       // padded: 1 counter / 64B
    int*    offs   = (int*)take((size_t)(N + 1) * 4);
    uint*   epack  = (uint*)take((size_t)E * 4);
    int*    bsum   = (int*)take((size_t)scanB * 4);

    hipMemsetAsync(hist, 0, (size_t)N * 64, stream);

    k_ln1<<<(N + 3) / 4, 256, 0, stream>>>(x, ntyp, conv_gamma, conv_beta, ybuf, N);
    k_cvt<<<13, 256, 0, stream>>>(W_rel, W_root, W_mlp, Wt);

    k_ehist<<<(E + 255) / 256, 256, 0, stream>>>(edst, hist, E);
    k_scan1<<<scanB, 256, 0, stream>>>(hist, bsum, N);
    k_scan2<<<1, 64, 0, stream>>>(bsum, offs, scanB, N);
    k_scan3<<<scanB, 256, 0, stream>>>(hist, bsum, offs, cursor, N);
    k_escatter<<<(E + 255) / 256, 256, 0, stream>>>(edst, esrc, etyp, cursor, epack, E);

    k_zagg<<<(N + 3) / 4, 256, 0, stream>>>(ybuf, offs, epack, zbuf, N);

    k_gemm2<<<(N + 63) / 64, 256, 0, stream>>>(ybuf, zbuf, Wt, x, ntyp,
                                               mlp_gamma, mlp_beta, x2, y2, N);

    k_mlp<<<(N + 63) / 64, 256, 0, stream>>>(y2, x2, ntyp, Wt, b_mlp, out, N);
}

// Round 11
// 292.107 us; speedup vs baseline: 1.4356x; 1.1100x over previous
//
#include <hip/hip_runtime.h>
#include <hip/hip_bf16.h>

#define D 128
#define EPS 1e-5f
#define CHK 8192            // edges per phase-1 chunk
#define P2CAP 6144          // max edges per 256-dst bucket (Poisson(4081)+32 sigma)

typedef __attribute__((ext_vector_type(8))) short short8;
typedef __attribute__((ext_vector_type(4))) float float4v;

__device__ inline ushort f2bf(float f) {
    __hip_bfloat16 b = __float2bfloat16(f);
    return *reinterpret_cast<ushort*>(&b);
}
__device__ inline float bf_lo(uint u) { return __uint_as_float(u << 16); }
__device__ inline float bf_hi(uint u) { return __uint_as_float(u & 0xffff0000u); }

// ---------- K1: LN1 + ReLU, fp32 in -> bf16 out. One wave per node. ----------
__global__ void k_ln1(const float* __restrict__ x, const int* __restrict__ ntp,
                      const float* __restrict__ gamma, const float* __restrict__ beta,
                      ushort* __restrict__ y, int N) {
    int n = blockIdx.x * 4 + (threadIdx.x >> 6);
    if (n >= N) return;
    int l = threadIdx.x & 63;
    float2 v = *(const float2*)(x + (size_t)n * D + 2 * l);
    float s = v.x + v.y, s2 = v.x * v.x + v.y * v.y;
    #pragma unroll
    for (int o = 32; o; o >>= 1) { s += __shfl_xor(s, o, 64); s2 += __shfl_xor(s2, o, 64); }
    float mu = s * (1.0f / D);
    float var = s2 * (1.0f / D) - mu * mu;
    float inv = rsqrtf(var + EPS);
    int t = ntp[n];
    float2 g = *(const float2*)(gamma + t * D + 2 * l);
    float2 b = *(const float2*)(beta + t * D + 2 * l);
    float a0 = fmaxf((v.x - mu) * inv * g.x + b.x, 0.0f);
    float a1 = fmaxf((v.y - mu) * inv * g.y + b.y, 0.0f);
    ((uint*)(y + (size_t)n * D))[l] = ((uint)f2bf(a1) << 16) | f2bf(a0);
}

// ---------- K2: weights -> bf16 in MFMA B-FRAGMENT order ----------------------
// m==0: W_root, 1..8: W_rel[m-1], 9..12: W_mlp[m-9].
__global__ void k_cvt(const float* __restrict__ Wrel, const float* __restrict__ Wroot,
                      const float* __restrict__ Wmlp, ushort* __restrict__ Wt) {
    __shared__ ushort t[128][136];
    int m = blockIdx.x;
    const float* src = (m == 0) ? Wroot
                     : (m <= 8) ? Wrel + (size_t)(m - 1) * D * D
                                : Wmlp + (size_t)(m - 9) * D * D;
    for (int i = threadIdx.x; i < D * D; i += 256) {
        int k = i >> 7, n = i & 127;
        t[n][k] = f2bf(src[i]);
    }
    __syncthreads();
    ushort* dst = Wt + (size_t)m * D * D;
    for (int i = threadIdx.x; i < D * D; i += 256) {
        int frag = i >> 9;            // 0..31  (nt*4+ks)
        int lane = (i >> 3) & 63;
        int j = i & 7;
        int nt = frag >> 2, ks = frag & 3;
        int n = nt * 16 + (lane & 15);
        int k = ks * 32 + (lane >> 4) * 8 + j;
        dst[i] = t[n][k];
    }
}

// ---------- two-phase edge sort by dst (block-owned write regions) ------------
// c1: per-chunk LDS histogram over coarse buckets (dst>>8)
__global__ void k_c1(const int* __restrict__ edst, int* __restrict__ hist, int E, int B) {
    __shared__ int cnt[256];
    int c = blockIdx.x, tid = threadIdx.x;
    cnt[tid] = 0;
    __syncthreads();
    #pragma unroll 4
    for (int k = 0; k < CHK / 256; ++k) {
        int e = c * CHK + k * 256 + tid;
        if (e < E) atomicAdd(&cnt[edst[e] >> 8], 1);
    }
    __syncthreads();
    if (tid < B) hist[c * B + tid] = cnt[tid];
}
// c2: per-bucket column scan over chunks -> chunkoff + bucktot
__global__ void k_c2(const int* __restrict__ hist, int* __restrict__ chunkoff,
                     int* __restrict__ bucktot, int C, int B) {
    __shared__ int v[128];
    int b = blockIdx.x, t = threadIdx.x;
    v[t] = (t < C) ? hist[t * B + b] : 0;
    __syncthreads();
    if (t == 0) {
        int s = 0;
        for (int c = 0; c < C; ++c) { int x = v[c]; v[c] = s; s += x; }
        bucktot[b] = s;
    }
    __syncthreads();
    if (t < C) chunkoff[t * B + b] = v[t];
}
// c3: exclusive scan of bucket totals -> buckbase
__global__ void k_c3(const int* __restrict__ bucktot, int* __restrict__ buckbase, int B) {
    if (threadIdx.x == 0) {
        int o = 0;
        for (int b = 0; b < B; ++b) { buckbase[b] = o; o += bucktot[b]; }
        buckbase[B] = o;
    }
}
// p1s: scatter edges into bucket-major edata; each chunk's runs written by ONE block
__global__ void k_p1s(const int* __restrict__ edst, const int* __restrict__ esrc,
                      const int* __restrict__ etyp, const int* __restrict__ buckbase,
                      const int* __restrict__ chunkoff, uint* __restrict__ edata,
                      int E, int B) {
    __shared__ int base[256];
    __shared__ int cnt[256];
    int c = blockIdx.x, tid = threadIdx.x;
    if (tid < B) base[tid] = buckbase[tid] + chunkoff[c * B + tid];
    cnt[tid] = 0;
    __syncthreads();
    #pragma unroll 4
    for (int k = 0; k < CHK / 256; ++k) {
        int e = c * CHK + k * 256 + tid;
        if (e < E) {
            int d = edst[e];
            int b = d >> 8;
            int r = atomicAdd(&cnt[b], 1);
            edata[base[b] + r] =
                ((uint)esrc[e] << 12) | ((uint)(d & 255) << 4) | (uint)etyp[e];
        }
    }
}
// p2: exact counting-sort within each 256-dst bucket (LDS), emit epack + offs
__global__ void k_p2(const uint* __restrict__ edata, const int* __restrict__ buckbase,
                     uint* __restrict__ epack, int* __restrict__ offs,
                     int N, int E, int B) {
    __shared__ uint ed[P2CAP];
    __shared__ int cnt[256], off[256], cur[256];
    int b = blockIdx.x, tid = threadIdx.x;
    int j0 = buckbase[b];
    int count = buckbase[b + 1] - j0;
    if (count > P2CAP) count = P2CAP;          // safety (statistically unreachable)
    for (int i = tid; i < count; i += 256) ed[i] = edata[j0 + i];
    cnt[tid] = 0;
    __syncthreads();
    for (int i = tid; i < count; i += 256) atomicAdd(&cnt[(ed[i] >> 4) & 255], 1);
    __syncthreads();
    if (tid == 0) {
        int s = 0;
        for (int i = 0; i < 256; ++i) { off[i] = s; cur[i] = s; s += cnt[i]; }
    }
    __syncthreads();
    for (int i = tid; i < count; i += 256) {
        uint v = ed[i];
        int dl = (v >> 4) & 255;
        int r = atomicAdd(&cur[dl], 1);
        epack[j0 + r] = ((v & 15u) << 28) | (v >> 12);
    }
    int v = b * 256 + tid;
    if (v < N) offs[v] = j0 + off[tid];
    if (b == 0 && tid == 0) offs[N] = E;
}

// ---------- K3: z[v][r] = sum of y[src] over edges (dst=v, type=r) ------------
// one wave per dst; NAMED register accumulators + wave-uniform switch; 4 loads
// in flight per step.
__global__ void k_zagg(const ushort* __restrict__ ybuf, const int* __restrict__ offs,
                       const uint* __restrict__ epack, ushort* __restrict__ zbuf, int N) {
    int wave = threadIdx.x >> 6;
    int l = threadIdx.x & 63;
    int v = blockIdx.x * 4 + wave;
    if (v >= N) return;
    float2 a0 = {0.f,0.f}, a1 = {0.f,0.f}, a2 = {0.f,0.f}, a3 = {0.f,0.f};
    float2 a4 = {0.f,0.f}, a5 = {0.f,0.f}, a6 = {0.f,0.f}, a7 = {0.f,0.f};
    const uint* yb = (const uint*)ybuf;
    int j = offs[v], e1 = offs[v + 1];

#define ZACC(P, U) do {                                                   \
        float lo = bf_lo(U), hi = bf_hi(U);                               \
        switch ((P) >> 28) {                                              \
            case 0: a0.x += lo; a0.y += hi; break;                        \
            case 1: a1.x += lo; a1.y += hi; break;                        \
            case 2: a2.x += lo; a2.y += hi; break;                        \
            case 3: a3.x += lo; a3.y += hi; break;                        \
            case 4: a4.x += lo; a4.y += hi; break;                        \
            case 5: a5.x += lo; a5.y += hi; break;                        \
            case 6: a6.x += lo; a6.y += hi; break;                        \
            default: a7.x += lo; a7.y += hi; break;                       \
        }                                                                 \
    } while (0)

    while (j < e1) {
        int chunk = min(64, e1 - j);
        uint pl = (j + l < e1) ? epack[j + l] : 0;
        int i = 0;
        for (; i + 3 < chunk; i += 4) {
            uint p0 = __shfl(pl, i, 64);
            uint p1 = __shfl(pl, i + 1, 64);
            uint p2 = __shfl(pl, i + 2, 64);
            uint p3 = __shfl(pl, i + 3, 64);
            uint u0 = yb[(size_t)(p0 & 0x0FFFFFFFu) * 64 + l];
            uint u1 = yb[(size_t)(p1 & 0x0FFFFFFFu) * 64 + l];
            uint u2 = yb[(size_t)(p2 & 0x0FFFFFFFu) * 64 + l];
            uint u3 = yb[(size_t)(p3 & 0x0FFFFFFFu) * 64 + l];
            ZACC(p0, u0); ZACC(p1, u1); ZACC(p2, u2); ZACC(p3, u3);
        }
        for (; i < chunk; ++i) {
            uint p = __shfl(pl, i, 64);
            uint u = yb[(size_t)(p & 0x0FFFFFFFu) * 64 + l];
            ZACC(p, u);
        }
        j += chunk;
    }
#undef ZACC
    uint* zrow = (uint*)(zbuf + (size_t)v * 1024);
    zrow[0 * 64 + l] = ((uint)f2bf(a0.y) << 16) | f2bf(a0.x);
    zrow[1 * 64 + l] = ((uint)f2bf(a1.y) << 16) | f2bf(a1.x);
    zrow[2 * 64 + l] = ((uint)f2bf(a2.y) << 16) | f2bf(a2.x);
    zrow[3 * 64 + l] = ((uint)f2bf(a3.y) << 16) | f2bf(a3.x);
    zrow[4 * 64 + l] = ((uint)f2bf(a4.y) << 16) | f2bf(a4.x);
    zrow[5 * 64 + l] = ((uint)f2bf(a5.y) << 16) | f2bf(a5.x);
    zrow[6 * 64 + l] = ((uint)f2bf(a6.y) << 16) | f2bf(a6.x);
    zrow[7 * 64 + l] = ((uint)f2bf(a7.y) << 16) | f2bf(a7.x);
}

// ---------- K4: agg = [y|z] @ [Wroot;Wrel] (K=1152) + x, fused LN2+ReLU -------
// grid ceil(N/64), block 256 (4 waves x 16 rows). W staged in LDS (frag order).
__launch_bounds__(256)
__global__ void k_gemm2(const ushort* __restrict__ ybuf, const ushort* __restrict__ zbuf,
                        const ushort* __restrict__ Wt, const float* __restrict__ x,
                        const int* __restrict__ ntp,
                        const float* __restrict__ gamma, const float* __restrict__ beta,
                        float* __restrict__ x2, ushort* __restrict__ y2, int N) {
    __shared__ ushort wsm[16384];                       // 32 KB
    int tid = threadIdx.x;
    int wave = tid >> 6, lane = tid & 63;
    int quad = lane >> 4, l15 = lane & 15;
    int base = blockIdx.x * 64 + wave * 16;
    int arow = min(base + l15, N - 1);
    const ushort* yrow = ybuf + (size_t)arow * 128;
    const ushort* zrow = zbuf + (size_t)arow * 1024;

    float4v acc[8];
    #pragma unroll
    for (int nt = 0; nt < 8; ++nt) acc[nt] = (float4v){0.f, 0.f, 0.f, 0.f};

    for (int mat = 0; mat < 9; ++mat) {
        __syncthreads();                                // protect wsm overwrite
        const ushort* wsrc = Wt + (size_t)mat * 16384;
        #pragma unroll
        for (int jj = 0; jj < 8; ++jj)
            *(uint4*)(wsm + jj * 2048 + tid * 8) = *(const uint4*)(wsrc + jj * 2048 + tid * 8);
        __syncthreads();
        const ushort* ap = (mat == 0) ? yrow : zrow + (mat - 1) * 128;
        short8 a[4];
        #pragma unroll
        for (int ks = 0; ks < 4; ++ks) a[ks] = *(const short8*)(ap + ks * 32 + quad * 8);
        #pragma unroll
        for (int nt = 0; nt < 8; ++nt) {
            #pragma unroll
            for (int ks = 0; ks < 4; ++ks) {
                short8 b = *(const short8*)(wsm + (((nt * 4 + ks) * 64 + lane) << 3));
                acc[nt] = __builtin_amdgcn_mfma_f32_16x16x32_bf16(a[ks], b, acc[nt], 0, 0, 0);
            }
        }
    }

    // epilogue: x2 = x + acc; LN2 + ReLU -> y2
    float s[4] = {0.f, 0.f, 0.f, 0.f}, s2[4] = {0.f, 0.f, 0.f, 0.f};
    #pragma unroll
    for (int nt = 0; nt < 8; ++nt) {
        int col = nt * 16 + l15;
        #pragma unroll
        for (int r = 0; r < 4; ++r) {
            int row = base + quad * 4 + r;
            float xv = (row < N) ? x[(size_t)row * D + col] : 0.f;
            float t = acc[nt][r] + xv;
            acc[nt][r] = t;
            s[r] += t; s2[r] += t * t;
        }
    }
    #pragma unroll
    for (int r = 0; r < 4; ++r) {
        #pragma unroll
        for (int o = 1; o < 16; o <<= 1) {
            s[r]  += __shfl_xor(s[r],  o, 64);
            s2[r] += __shfl_xor(s2[r], o, 64);
        }
    }
    #pragma unroll
    for (int r = 0; r < 4; ++r) {
        int row = base + quad * 4 + r;
        int rc = min(row, N - 1);
        int t = ntp[rc];
        float mu  = s[r] * (1.0f / D);
        float var = s2[r] * (1.0f / D) - mu * mu;
        float inv = rsqrtf(var + EPS);
        #pragma unroll
        for (int nt = 0; nt < 8; ++nt) {
            int col = nt * 16 + l15;
            float xx = acc[nt][r];
            float yn = fmaxf((xx - mu) * inv * gamma[t * D + col] + beta[t * D + col], 0.f);
            if (row < N) {
                x2[(size_t)row * D + col] = xx;
                y2[(size_t)row * D + col] = f2bf(yn);
            }
        }
    }
}

// ---------- K5: MLP for ALL 4 types + per-row select + residual + bias --------
__global__ void k_mlp(const ushort* __restrict__ y2, const float* __restrict__ x2,
                      const int* __restrict__ ntp,
                      const ushort* __restrict__ Wt, const float* __restrict__ bmlp,
                      float* __restrict__ out, int N) {
    int wave = threadIdx.x >> 6;
    int lane = threadIdx.x & 63;
    int quad = lane >> 4, l15 = lane & 15;
    int base = blockIdx.x * 64 + wave * 16;
    int arow = min(base + l15, N - 1);
    short8 a[4];
    const ushort* yrow = y2 + (size_t)arow * D + quad * 8;
    #pragma unroll
    for (int ks = 0; ks < 4; ++ks) a[ks] = *(const short8*)(yrow + ks * 32);
    int ty[4];
    #pragma unroll
    for (int r = 0; r < 4; ++r) ty[r] = ntp[min(base + quad * 4 + r, N - 1)];
    const ushort* W0 = Wt + (size_t)9  * D * D;
    const ushort* W1 = Wt + (size_t)10 * D * D;
    const ushort* W2 = Wt + (size_t)11 * D * D;
    const ushort* W3 = Wt + (size_t)12 * D * D;
    #pragma unroll
    for (int nt = 0; nt < 8; ++nt) {
        float4v c0 = {0.f,0.f,0.f,0.f}, c1 = {0.f,0.f,0.f,0.f};
        float4v c2 = {0.f,0.f,0.f,0.f}, c3 = {0.f,0.f,0.f,0.f};
        #pragma unroll
        for (int ks = 0; ks < 4; ++ks) {
            int fo = ((nt * 4 + ks) * 64 + lane) << 3;
            short8 b0 = *(const short8*)(W0 + fo);
            short8 b1 = *(const short8*)(W1 + fo);
            short8 b2 = *(const short8*)(W2 + fo);
            short8 b3 = *(const short8*)(W3 + fo);
            c0 = __builtin_amdgcn_mfma_f32_16x16x32_bf16(a[ks], b0, c0, 0, 0, 0);
            c1 = __builtin_amdgcn_mfma_f32_16x16x32_bf16(a[ks], b1, c1, 0, 0, 0);
            c2 = __builtin_amdgcn_mfma_f32_16x16x32_bf16(a[ks], b2, c2, 0, 0, 0);
            c3 = __builtin_amdgcn_mfma_f32_16x16x32_bf16(a[ks], b3, c3, 0, 0, 0);
        }
        int col = nt * 16 + l15;
        #pragma unroll
        for (int r = 0; r < 4; ++r) {
            int row = base + quad * 4 + r;
            if (row < N) {
                int t = ty[r];
                float v = (t == 0) ? c0[r] : (t == 1) ? c1[r] : (t == 2) ? c2[r] : c3[r];
                out[(size_t)row * D + col] =
                    x2[(size_t)row * D + col] + v + bmlp[t * D + col];
            }
        }
    }
}

// ---------- launch ------------------------------------------------------------
extern "C" void kernel_launch(void* const* d_in, const int* in_sizes, int n_in,
                              void* d_out, int out_size, void* d_ws, size_t ws_size,
                              hipStream_t stream) {
    const float* x          = (const float*)d_in[0];
    const int*   esrc       = (const int*)d_in[1];
    const int*   edst       = (const int*)d_in[2];
    const int*   ntyp       = (const int*)d_in[3];
    const int*   etyp       = (const int*)d_in[4];
    const float* conv_gamma = (const float*)d_in[5];
    const float* conv_beta  = (const float*)d_in[6];
    const float* W_rel      = (const float*)d_in[7];
    const float* W_root     = (const float*)d_in[8];
    const float* mlp_gamma  = (const float*)d_in[9];
    const float* mlp_beta   = (const float*)d_in[10];
    const float* W_mlp      = (const float*)d_in[11];
    const float* b_mlp      = (const float*)d_in[12];
    float* out = (float*)d_out;

    int N = in_sizes[0] / D;
    int E = in_sizes[1];
    int C = (E + CHK - 1) / CHK;        // chunks
    int B = (N + 255) / 256;            // coarse buckets (dst>>8)

    char* p = (char*)d_ws;
    auto take = [&p](size_t bytes) { char* q = p; p += (bytes + 255) & ~(size_t)255; return q; };
    ushort* ybuf    = (ushort*)take((size_t)N * D * 2);
    ushort* y2      = (ushort*)take((size_t)N * D * 2);
    ushort* zbuf    = (ushort*)take((size_t)N * 1024 * 2);
    float*  x2      = (float*)take((size_t)N * D * 4);
    ushort* Wt      = (ushort*)take((size_t)13 * D * D * 2);
    uint*   edata   = (uint*)take((size_t)E * 4);
    uint*   epack   = (uint*)take((size_t)E * 4);
    int*    offs    = (int*)take((size_t)(N + 1) * 4);
    int*    hist    = (int*)take((size_t)C * B * 4);
    int*    chunkoff= (int*)take((size_t)C * B * 4);
    int*    bucktot = (int*)take((size_t)B * 4);
    int*    buckbase= (int*)take((size_t)(B + 1) * 4);

    k_ln1<<<(N + 3) / 4, 256, 0, stream>>>(x, ntyp, conv_gamma, conv_beta, ybuf, N);
    k_cvt<<<13, 256, 0, stream>>>(W_rel, W_root, W_mlp, Wt);

    k_c1<<<C, 256, 0, stream>>>(edst, hist, E, B);
    k_c2<<<B, 128, 0, stream>>>(hist, chunkoff, bucktot, C, B);
    k_c3<<<1, 64, 0, stream>>>(bucktot, buckbase, B);
    k_p1s<<<C, 256, 0, stream>>>(edst, esrc, etyp, buckbase, chunkoff, edata, E, B);
    k_p2<<<B, 256, 0, stream>>>(edata, buckbase, epack, offs, N, E, B);

    k_zagg<<<(N + 3) / 4, 256, 0, stream>>>(ybuf, offs, epack, zbuf, N);

    k_gemm2<<<(N + 63) / 64, 256, 0, stream>>>(ybuf, zbuf, Wt, x, ntyp,
                                               mlp_gamma, mlp_beta, x2, y2, N);

    k_mlp<<<(N + 63) / 64, 256, 0, stream>>>(y2, x2, ntyp, Wt, b_mlp, out, N);
}

// Round 12
// 289.460 us; speedup vs baseline: 1.4487x; 1.0091x over previous
//
#include <hip/hip_runtime.h>
#include <hip/hip_bf16.h>

#define D 128
#define EPS 1e-5f
#define CHK 8192            // edges per phase-1 chunk
#define P2CAP 6144          // max edges per 256-dst bucket

typedef __attribute__((ext_vector_type(8))) short short8;
typedef __attribute__((ext_vector_type(4))) float float4v;

__device__ inline ushort f2bf(float f) {
    __hip_bfloat16 b = __float2bfloat16(f);
    return *reinterpret_cast<ushort*>(&b);
}
__device__ inline float bf_lo(uint u) { return __uint_as_float(u << 16); }
__device__ inline float bf_hi(uint u) { return __uint_as_float(u & 0xffff0000u); }

// ---------- K1: fused weight-convert (blocks 0..12) + LN1+ReLU (rest) ---------
// cvt: m==0 W_root, 1..8 W_rel[m-1], 9..12 W_mlp[m-9] -> bf16 B-fragment order.
__global__ void k_ln1cvt(const float* __restrict__ x, const int* __restrict__ ntp,
                         const float* __restrict__ gamma, const float* __restrict__ beta,
                         ushort* __restrict__ y,
                         const float* __restrict__ Wrel, const float* __restrict__ Wroot,
                         const float* __restrict__ Wmlp, ushort* __restrict__ Wt, int N) {
    __shared__ ushort t[128][136];
    if (blockIdx.x < 13) {
        int m = blockIdx.x;
        const float* src = (m == 0) ? Wroot
                         : (m <= 8) ? Wrel + (size_t)(m - 1) * D * D
                                    : Wmlp + (size_t)(m - 9) * D * D;
        for (int i = threadIdx.x; i < D * D; i += 256) {
            int k = i >> 7, n = i & 127;
            t[n][k] = f2bf(src[i]);
        }
        __syncthreads();
        ushort* dst = Wt + (size_t)m * D * D;
        for (int i = threadIdx.x; i < D * D; i += 256) {
            int frag = i >> 9;
            int lane = (i >> 3) & 63;
            int j = i & 7;
            int nt = frag >> 2, ks = frag & 3;
            int n = nt * 16 + (lane & 15);
            int k = ks * 32 + (lane >> 4) * 8 + j;
            dst[i] = t[n][k];
        }
        return;
    }
    int n = (blockIdx.x - 13) * 4 + (threadIdx.x >> 6);
    if (n >= N) return;
    int l = threadIdx.x & 63;
    float2 v = *(const float2*)(x + (size_t)n * D + 2 * l);
    float s = v.x + v.y, s2 = v.x * v.x + v.y * v.y;
    #pragma unroll
    for (int o = 32; o; o >>= 1) { s += __shfl_xor(s, o, 64); s2 += __shfl_xor(s2, o, 64); }
    float mu = s * (1.0f / D);
    float var = s2 * (1.0f / D) - mu * mu;
    float inv = rsqrtf(var + EPS);
    int tt = ntp[n];
    float2 g = *(const float2*)(gamma + tt * D + 2 * l);
    float2 b = *(const float2*)(beta + tt * D + 2 * l);
    float a0 = fmaxf((v.x - mu) * inv * g.x + b.x, 0.0f);
    float a1 = fmaxf((v.y - mu) * inv * g.y + b.y, 0.0f);
    ((uint*)(y + (size_t)n * D))[l] = ((uint)f2bf(a1) << 16) | f2bf(a0);
}

// ---------- two-phase edge sort by dst (block-owned write regions) ------------
__global__ void k_c1(const int* __restrict__ edst, int* __restrict__ hist, int E, int B) {
    __shared__ int cnt[256];
    int c = blockIdx.x, tid = threadIdx.x;
    cnt[tid] = 0;
    __syncthreads();
    #pragma unroll 4
    for (int k = 0; k < CHK / 256; ++k) {
        int e = c * CHK + k * 256 + tid;
        if (e < E) atomicAdd(&cnt[edst[e] >> 8], 1);
    }
    __syncthreads();
    if (tid < B) hist[c * B + tid] = cnt[tid];
}
__global__ void k_c2(const int* __restrict__ hist, int* __restrict__ chunkoff,
                     int* __restrict__ bucktot, int C, int B) {
    __shared__ int v[128];
    int b = blockIdx.x, t = threadIdx.x;
    v[t] = (t < C) ? hist[t * B + b] : 0;
    __syncthreads();
    if (t == 0) {
        int s = 0;
        for (int c = 0; c < C; ++c) { int x = v[c]; v[c] = s; s += x; }
        bucktot[b] = s;
    }
    __syncthreads();
    if (t < C) chunkoff[t * B + b] = v[t];
}
// p1s: scatter edges into bucket-major edata; in-block scan of bucktot -> base
__global__ void k_p1s(const int* __restrict__ edst, const int* __restrict__ esrc,
                      const int* __restrict__ etyp, const int* __restrict__ bucktot,
                      const int* __restrict__ chunkoff, uint* __restrict__ edata,
                      int E, int B) {
    __shared__ int ps[256];
    __shared__ int base[256];
    __shared__ int cnt[256];
    int c = blockIdx.x, tid = threadIdx.x;
    int bt = (tid < B) ? bucktot[tid] : 0;
    ps[tid] = bt;
    __syncthreads();
    for (int o = 1; o < 256; o <<= 1) {
        int v = (tid >= o) ? ps[tid - o] : 0;
        __syncthreads();
        ps[tid] += v;
        __syncthreads();
    }
    base[tid] = (ps[tid] - bt) + ((tid < B) ? chunkoff[c * B + tid] : 0);
    cnt[tid] = 0;
    __syncthreads();
    #pragma unroll 4
    for (int k = 0; k < CHK / 256; ++k) {
        int e = c * CHK + k * 256 + tid;
        if (e < E) {
            int d = edst[e];
            int b = d >> 8;
            int r = atomicAdd(&cnt[b], 1);
            edata[base[b] + r] =
                ((uint)esrc[e] << 12) | ((uint)(d & 255) << 4) | (uint)etyp[e];
        }
    }
}
// p2: exact counting-sort within each 256-dst bucket; in-block scan for j0
__global__ void k_p2(const uint* __restrict__ edata, const int* __restrict__ bucktot,
                     uint* __restrict__ epack, int* __restrict__ offs,
                     int N, int E, int B) {
    __shared__ int ps[256];
    __shared__ uint ed[P2CAP];
    __shared__ int cnt[256], off[256], cur[256];
    int b = blockIdx.x, tid = threadIdx.x;
    int bt = (tid < B) ? bucktot[tid] : 0;
    ps[tid] = bt;
    __syncthreads();
    for (int o = 1; o < 256; o <<= 1) {
        int v = (tid >= o) ? ps[tid - o] : 0;
        __syncthreads();
        ps[tid] += v;
        __syncthreads();
    }
    int j0 = ps[b] - ((b < B) ? bucktot[b] : 0);   // exclusive prefix of bucket b
    int count = ps[b] - j0;
    if (count > P2CAP) count = P2CAP;
    for (int i = tid; i < count; i += 256) ed[i] = edata[j0 + i];
    cnt[tid] = 0;
    __syncthreads();
    for (int i = tid; i < count; i += 256) atomicAdd(&cnt[(ed[i] >> 4) & 255], 1);
    __syncthreads();
    if (tid == 0) {
        int s = 0;
        for (int i = 0; i < 256; ++i) { off[i] = s; cur[i] = s; s += cnt[i]; }
    }
    __syncthreads();
    for (int i = tid; i < count; i += 256) {
        uint v = ed[i];
        int dl = (v >> 4) & 255;
        int r = atomicAdd(&cur[dl], 1);
        epack[j0 + r] = ((v & 15u) << 28) | (v >> 12);
    }
    int v = b * 256 + tid;
    if (v < N) offs[v] = j0 + off[tid];
    if (b == 0 && tid == 0) offs[N] = E;
}

// ---------- K3: z[v][r] = sum of y[src] over edges (dst=v, type=r) ------------
__global__ void k_zagg(const ushort* __restrict__ ybuf, const int* __restrict__ offs,
                       const uint* __restrict__ epack, ushort* __restrict__ zbuf, int N) {
    int wave = threadIdx.x >> 6;
    int l = threadIdx.x & 63;
    int v = blockIdx.x * 4 + wave;
    if (v >= N) return;
    float2 a0 = {0.f,0.f}, a1 = {0.f,0.f}, a2 = {0.f,0.f}, a3 = {0.f,0.f};
    float2 a4 = {0.f,0.f}, a5 = {0.f,0.f}, a6 = {0.f,0.f}, a7 = {0.f,0.f};
    const uint* yb = (const uint*)ybuf;
    int j = offs[v], e1 = offs[v + 1];

#define ZACC(P, U) do {                                                   \
        float lo = bf_lo(U), hi = bf_hi(U);                               \
        switch ((P) >> 28) {                                              \
            case 0: a0.x += lo; a0.y += hi; break;                        \
            case 1: a1.x += lo; a1.y += hi; break;                        \
            case 2: a2.x += lo; a2.y += hi; break;                        \
            case 3: a3.x += lo; a3.y += hi; break;                        \
            case 4: a4.x += lo; a4.y += hi; break;                        \
            case 5: a5.x += lo; a5.y += hi; break;                        \
            case 6: a6.x += lo; a6.y += hi; break;                        \
            default: a7.x += lo; a7.y += hi; break;                       \
        }                                                                 \
    } while (0)

    while (j < e1) {
        int chunk = min(64, e1 - j);
        uint pl = (j + l < e1) ? epack[j + l] : 0;
        int i = 0;
        for (; i + 3 < chunk; i += 4) {
            uint p0 = __shfl(pl, i, 64);
            uint p1 = __shfl(pl, i + 1, 64);
            uint p2 = __shfl(pl, i + 2, 64);
            uint p3 = __shfl(pl, i + 3, 64);
            uint u0 = yb[(size_t)(p0 & 0x0FFFFFFFu) * 64 + l];
            uint u1 = yb[(size_t)(p1 & 0x0FFFFFFFu) * 64 + l];
            uint u2 = yb[(size_t)(p2 & 0x0FFFFFFFu) * 64 + l];
            uint u3 = yb[(size_t)(p3 & 0x0FFFFFFFu) * 64 + l];
            ZACC(p0, u0); ZACC(p1, u1); ZACC(p2, u2); ZACC(p3, u3);
        }
        for (; i < chunk; ++i) {
            uint p = __shfl(pl, i, 64);
            uint u = yb[(size_t)(p & 0x0FFFFFFFu) * 64 + l];
            ZACC(p, u);
        }
        j += chunk;
    }
#undef ZACC
    uint* zrow = (uint*)(zbuf + (size_t)v * 1024);
    zrow[0 * 64 + l] = ((uint)f2bf(a0.y) << 16) | f2bf(a0.x);
    zrow[1 * 64 + l] = ((uint)f2bf(a1.y) << 16) | f2bf(a1.x);
    zrow[2 * 64 + l] = ((uint)f2bf(a2.y) << 16) | f2bf(a2.x);
    zrow[3 * 64 + l] = ((uint)f2bf(a3.y) << 16) | f2bf(a3.x);
    zrow[4 * 64 + l] = ((uint)f2bf(a4.y) << 16) | f2bf(a4.x);
    zrow[5 * 64 + l] = ((uint)f2bf(a5.y) << 16) | f2bf(a5.x);
    zrow[6 * 64 + l] = ((uint)f2bf(a6.y) << 16) | f2bf(a6.x);
    zrow[7 * 64 + l] = ((uint)f2bf(a7.y) << 16) | f2bf(a7.x);
}

// ---------- K4: FUSED conv-GEMM (K=1152) + LN2 + ReLU + MLP + residuals -------
// grid ceil(N/64), block 256. Conv: W staged in wsm (frag order). Then wsm is
// REUSED (after one barrier) as the 64x136 bf16 y2 tile: epilogue writes LN
// outputs, each wave reads back its own 16 rows as MLP A-fragments (intra-wave,
// stride 136 -> 2-way banks = free). x2 stays in registers; MLP computes all 4
// type variants (B-frags from global Wt, L2/L3-resident) and selects per row.
__launch_bounds__(256)
__global__ void k_gm(const ushort* __restrict__ ybuf, const ushort* __restrict__ zbuf,
                     const ushort* __restrict__ Wt, const float* __restrict__ x,
                     const int* __restrict__ ntp,
                     const float* __restrict__ gamma, const float* __restrict__ beta,
                     const float* __restrict__ bmlp, float* __restrict__ out, int N) {
    __shared__ ushort wsm[16384];                       // 32 KB
    int tid = threadIdx.x;
    int wave = tid >> 6, lane = tid & 63;
    int quad = lane >> 4, l15 = lane & 15;
    int base = blockIdx.x * 64 + wave * 16;
    int arow = min(base + l15, N - 1);
    const ushort* yrow = ybuf + (size_t)arow * 128;
    const ushort* zrow = zbuf + (size_t)arow * 1024;

    float4v acc[8];
    #pragma unroll
    for (int nt = 0; nt < 8; ++nt) acc[nt] = (float4v){0.f, 0.f, 0.f, 0.f};

    for (int mat = 0; mat < 9; ++mat) {
        __syncthreads();
        const ushort* wsrc = Wt + (size_t)mat * 16384;
        #pragma unroll
        for (int jj = 0; jj < 8; ++jj)
            *(uint4*)(wsm + jj * 2048 + tid * 8) = *(const uint4*)(wsrc + jj * 2048 + tid * 8);
        __syncthreads();
        const ushort* ap = (mat == 0) ? yrow : zrow + (mat - 1) * 128;
        short8 a[4];
        #pragma unroll
        for (int ks = 0; ks < 4; ++ks) a[ks] = *(const short8*)(ap + ks * 32 + quad * 8);
        #pragma unroll
        for (int nt = 0; nt < 8; ++nt) {
            #pragma unroll
            for (int ks = 0; ks < 4; ++ks) {
                short8 b = *(const short8*)(wsm + (((nt * 4 + ks) * 64 + lane) << 3));
                acc[nt] = __builtin_amdgcn_mfma_f32_16x16x32_bf16(a[ks], b, acc[nt], 0, 0, 0);
            }
        }
    }

    // epilogue: x2 = x + acc (kept in acc); LN2 + ReLU -> y2 tile in wsm
    __syncthreads();                                    // all waves done with W in wsm
    float s[4] = {0.f, 0.f, 0.f, 0.f}, s2[4] = {0.f, 0.f, 0.f, 0.f};
    #pragma unroll
    for (int nt = 0; nt < 8; ++nt) {
        int col = nt * 16 + l15;
        #pragma unroll
        for (int r = 0; r < 4; ++r) {
            int row = base + quad * 4 + r;
            float xv = (row < N) ? x[(size_t)row * D + col] : 0.f;
            float t = acc[nt][r] + xv;
            acc[nt][r] = t;
            s[r] += t; s2[r] += t * t;
        }
    }
    #pragma unroll
    for (int r = 0; r < 4; ++r) {
        #pragma unroll
        for (int o = 1; o < 16; o <<= 1) {
            s[r]  += __shfl_xor(s[r],  o, 64);
            s2[r] += __shfl_xor(s2[r], o, 64);
        }
    }
    int ty[4];
    #pragma unroll
    for (int r = 0; r < 4; ++r) {
        int rc = min(base + quad * 4 + r, N - 1);
        ty[r] = ntp[rc];
        float mu  = s[r] * (1.0f / D);
        float var = s2[r] * (1.0f / D) - mu * mu;
        float inv = rsqrtf(var + EPS);
        int lrow = wave * 16 + quad * 4 + r;            // row within block tile
        #pragma unroll
        for (int nt = 0; nt < 8; ++nt) {
            int col = nt * 16 + l15;
            float yn = fmaxf((acc[nt][r] - mu) * inv * gamma[ty[r] * D + col]
                             + beta[ty[r] * D + col], 0.f);
            wsm[lrow * 136 + col] = f2bf(yn);
        }
    }
    // MLP A-fragments: intra-wave LDS read-back (rows wave*16..+15 written above)
    short8 a2[4];
    const ushort* myrow = wsm + (wave * 16 + l15) * 136;
    #pragma unroll
    for (int ks = 0; ks < 4; ++ks) a2[ks] = *(const short8*)(myrow + ks * 32 + quad * 8);

    const ushort* W0 = Wt + (size_t)9  * D * D;
    const ushort* W1 = Wt + (size_t)10 * D * D;
    const ushort* W2 = Wt + (size_t)11 * D * D;
    const ushort* W3 = Wt + (size_t)12 * D * D;
    #pragma unroll
    for (int nt = 0; nt < 8; ++nt) {
        float4v c0 = {0.f,0.f,0.f,0.f}, c1 = {0.f,0.f,0.f,0.f};
        float4v c2 = {0.f,0.f,0.f,0.f}, c3 = {0.f,0.f,0.f,0.f};
        #pragma unroll
        for (int ks = 0; ks < 4; ++ks) {
            int fo = ((nt * 4 + ks) * 64 + lane) << 3;
            short8 b0 = *(const short8*)(W0 + fo);
            short8 b1 = *(const short8*)(W1 + fo);
            short8 b2 = *(const short8*)(W2 + fo);
            short8 b3 = *(const short8*)(W3 + fo);
            c0 = __builtin_amdgcn_mfma_f32_16x16x32_bf16(a2[ks], b0, c0, 0, 0, 0);
            c1 = __builtin_amdgcn_mfma_f32_16x16x32_bf16(a2[ks], b1, c1, 0, 0, 0);
            c2 = __builtin_amdgcn_mfma_f32_16x16x32_bf16(a2[ks], b2, c2, 0, 0, 0);
            c3 = __builtin_amdgcn_mfma_f32_16x16x32_bf16(a2[ks], b3, c3, 0, 0, 0);
        }
        int col = nt * 16 + l15;
        #pragma unroll
        for (int r = 0; r < 4; ++r) {
            int row = base + quad * 4 + r;
            if (row < N) {
                int t = ty[r];
                float v = (t == 0) ? c0[r] : (t == 1) ? c1[r] : (t == 2) ? c2[r] : c3[r];
                out[(size_t)row * D + col] = acc[nt][r] + v + bmlp[t * D + col];
            }
        }
    }
}

// ---------- launch ------------------------------------------------------------
extern "C" void kernel_launch(void* const* d_in, const int* in_sizes, int n_in,
                              void* d_out, int out_size, void* d_ws, size_t ws_size,
                              hipStream_t stream) {
    const float* x          = (const float*)d_in[0];
    const int*   esrc       = (const int*)d_in[1];
    const int*   edst       = (const int*)d_in[2];
    const int*   ntyp       = (const int*)d_in[3];
    const int*   etyp       = (const int*)d_in[4];
    const float* conv_gamma = (const float*)d_in[5];
    const float* conv_beta  = (const float*)d_in[6];
    const float* W_rel      = (const float*)d_in[7];
    const float* W_root     = (const float*)d_in[8];
    const float* mlp_gamma  = (const float*)d_in[9];
    const float* mlp_beta   = (const float*)d_in[10];
    const float* W_mlp      = (const float*)d_in[11];
    const float* b_mlp      = (const float*)d_in[12];
    float* out = (float*)d_out;

    int N = in_sizes[0] / D;
    int E = in_sizes[1];
    int C = (E + CHK - 1) / CHK;        // chunks (<=128)
    int B = (N + 255) / 256;            // coarse buckets (<=256)

    char* p = (char*)d_ws;
    auto take = [&p](size_t bytes) { char* q = p; p += (bytes + 255) & ~(size_t)255; return q; };
    ushort* ybuf    = (ushort*)take((size_t)N * D * 2);
    ushort* zbuf    = (ushort*)take((size_t)N * 1024 * 2);
    ushort* Wt      = (ushort*)take((size_t)13 * D * D * 2);
    uint*   edata   = (uint*)take((size_t)E * 4);
    uint*   epack   = (uint*)take((size_t)E * 4);
    int*    offs    = (int*)take((size_t)(N + 1) * 4);
    int*    hist    = (int*)take((size_t)C * B * 4);
    int*    chunkoff= (int*)take((size_t)C * B * 4);
    int*    bucktot = (int*)take((size_t)B * 4);

    k_ln1cvt<<<13 + (N + 3) / 4, 256, 0, stream>>>(x, ntyp, conv_gamma, conv_beta,
                                                   ybuf, W_rel, W_root, W_mlp, Wt, N);

    k_c1<<<C, 256, 0, stream>>>(edst, hist, E, B);
    k_c2<<<B, 128, 0, stream>>>(hist, chunkoff, bucktot, C, B);
    k_p1s<<<C, 256, 0, stream>>>(edst, esrc, etyp, bucktot, chunkoff, edata, E, B);
    k_p2<<<B, 256, 0, stream>>>(edata, bucktot, epack, offs, N, E, B);

    k_zagg<<<(N + 3) / 4, 256, 0, stream>>>(ybuf, offs, epack, zbuf, N);

    k_gm<<<(N + 63) / 64, 256, 0, stream>>>(ybuf, zbuf, Wt, x, ntyp,
                                            mlp_gamma, mlp_beta, b_mlp, out, N);
}